// Round 5
// baseline (729.020 us; speedup 1.0000x reference)
//
#include <hip/hip_runtime.h>
#include <hip/hip_bf16.h>
#include <math.h>
#include <stdint.h>

// ---- problem constants ----
#define S_LEN 4680
#define DIMSZ 1536
#define NH    12
#define HD    128
#define FRAME 1560
#define NGRP  74        // padded 64-key/-q groups (74*64 = 4736)
#define PANH  (NGRP * 8192)   // f16 elems per head in a panelized tensor
#define NSLOT 150       // (q-tile, chunk) slots per head: 12*2 + 12*4 + 13*6

typedef _Float16 f16;
typedef _Float16 f16x8 __attribute__((ext_vector_type(8)));
typedef _Float16 f16x4 __attribute__((ext_vector_type(4)));
typedef _Float16 f16x2 __attribute__((ext_vector_type(2)));
typedef __fp16   fp16x2 __attribute__((ext_vector_type(2)));
typedef float    f32x4  __attribute__((ext_vector_type(4)));
typedef float    f32x16 __attribute__((ext_vector_type(16)));
typedef int      v2i    __attribute__((ext_vector_type(2)));

__device__ __forceinline__ void async16(const void* g, void* l) {
    __builtin_amdgcn_global_load_lds((const __attribute__((address_space(1))) void*)g,
                                     (__attribute__((address_space(3))) void*)l, 16, 0, 0);
}

__device__ __forceinline__ float fexp2(float x) {
#if __has_builtin(__builtin_amdgcn_exp2f)
    return __builtin_amdgcn_exp2f(x);
#else
    return exp2f(x);
#endif
}

union PkCast { fp16x2 v; int i; };
union FragCast { int w[4]; f16x8 v; };

// ============================================================
// all f32->f16 casts in one dispatch: y=0 x, y=1..4 weights
// ============================================================
__global__ __launch_bounds__(256) void cast_all(const float* __restrict__ x,
                                                const float* __restrict__ wq,
                                                const float* __restrict__ wk,
                                                const float* __restrict__ wv,
                                                const float* __restrict__ wo,
                                                f16* __restrict__ xh,
                                                f16* __restrict__ wh) {
    int y = blockIdx.y;
    int i = blockIdx.x * 256 + threadIdx.x;
    if (y == 0) {
        if (i < (S_LEN * DIMSZ) / 4) {
            float4 v = ((const float4*)x)[i];
            f16x4 h; h[0]=(f16)v.x; h[1]=(f16)v.y; h[2]=(f16)v.z; h[3]=(f16)v.w;
            ((f16x4*)xh)[i] = h;
        }
    } else {
        const int nW4 = (DIMSZ * DIMSZ) / 4;
        if (i < nW4) {
            const float* src = (y==1)?wq:(y==2)?wk:(y==3)?wv:wo;
            float4 v = ((const float4*)src)[i];
            f16x4 h; h[0]=(f16)v.x; h[1]=(f16)v.y; h[2]=(f16)v.z; h[3]=(f16)v.w;
            ((f16x4*)wh)[(size_t)(y-1)*nW4 + i] = h;
        }
    }
}

// ============================================================
// Fused QKV GEMM (m97 structure), grid (37,12,3).
// z=0/1: pre-norm Q/K, f16 row-major. z=2: V, f16 panelized Vt.
// Vt panels: [head][key-group][8 kchunks][128 d][8 keys]
// ============================================================
__global__ __launch_bounds__(256) void gemm_qkv(const f16* __restrict__ A,
                                                const f16* __restrict__ Bq,
                                                const f16* __restrict__ Bk,
                                                const f16* __restrict__ Bv,
                                                const float* __restrict__ bq,
                                                const float* __restrict__ bk,
                                                const float* __restrict__ bv,
                                                f16* __restrict__ preq,
                                                f16* __restrict__ prek,
                                                f16* __restrict__ vtp) {
    int z = blockIdx.z;
    const f16* B = (z==0) ? Bq : (z==1) ? Bk : Bv;
    const float* bias = (z==0) ? bq : (z==1) ? bk : bv;

    __shared__ __align__(16) f16 Al[128 * 64];
    __shared__ __align__(16) f16 Bl[128 * 64];
    int tid = threadIdx.x;
    int lane = tid & 63, wv = tid >> 6;
    int l16 = lane & 15, quad = lane >> 4;
    int wr = (wv >> 1) * 64, wc = (wv & 1) * 64;
    int m0 = blockIdx.x * 128, n0 = blockIdx.y * 128;

    f32x4 acc[4][4] = {};

    for (int kb = 0; kb < DIMSZ; kb += 64) {
        __syncthreads();
#pragma unroll
        for (int j = 0; j < 4; j++) {
            int s = j * 256 + wv * 64 + lane;
            int r = s >> 3, cc = s & 7;
            const f16* src = A + (size_t)min(m0 + r, S_LEN - 1) * DIMSZ + kb + ((cc ^ (r & 7)) << 3);
            async16(src, (char*)Al + (j * 4096 + wv * 1024));
        }
#pragma unroll
        for (int j = 0; j < 4; j++) {
            int s = j * 256 + wv * 64 + lane;
            int r = s >> 3, cc = s & 7;
            const f16* src = B + (size_t)(n0 + r) * DIMSZ + kb + ((cc ^ (r & 7)) << 3);
            async16(src, (char*)Bl + (j * 4096 + wv * 1024));
        }
        __builtin_amdgcn_s_waitcnt(0x0f70);
        __syncthreads();

#pragma unroll
        for (int kc = 0; kc < 2; kc++) {
            f16x8 af[4], bf[4];
#pragma unroll
            for (int i = 0; i < 4; i++) {
                int ar = wr + i * 16 + l16;
                af[i] = *(const f16x8*)((const char*)Al + ar * 128 + (((kc * 4 + quad) ^ (ar & 7)) << 4));
                int br = wc + i * 16 + l16;
                bf[i] = *(const f16x8*)((const char*)Bl + br * 128 + (((kc * 4 + quad) ^ (br & 7)) << 4));
            }
#pragma unroll
            for (int mi = 0; mi < 4; mi++)
#pragma unroll
                for (int ni = 0; ni < 4; ni++)
                    acc[mi][ni] = __builtin_amdgcn_mfma_f32_16x16x32_f16(af[mi], bf[ni], acc[mi][ni], 0, 0, 0);
        }
    }

    if (z < 2) {
        f16* C = (z == 0) ? preq : prek;
#pragma unroll
        for (int mi = 0; mi < 4; mi++)
#pragma unroll
            for (int ni = 0; ni < 4; ni++) {
                int col = n0 + wc + ni * 16 + l16;
                float bv_ = bias[col];
#pragma unroll
                for (int r = 0; r < 4; r++) {
                    int row = m0 + wr + mi * 16 + quad * 4 + r;
                    if (row < S_LEN) C[(size_t)row * DIMSZ + col] = (f16)(acc[mi][ni][r] + bv_);
                }
            }
    } else {
#pragma unroll
        for (int mi = 0; mi < 4; mi++)
#pragma unroll
            for (int ni = 0; ni < 4; ni++) {
                int col  = n0 + wc + ni * 16 + l16;
                int vhead = col >> 7, d = col & 127;
                int base = m0 + wr + mi * 16 + quad * 4;   // 4 consecutive keys
                if (base < S_LEN) {
                    float bv_ = bias[col];
                    f16x4 h;
#pragma unroll
                    for (int r = 0; r < 4; r++) h[r] = (f16)(acc[mi][ni][r] + bv_);
                    size_t off = (size_t)vhead * PANH + (size_t)(base >> 6) * 8192
                               + ((base >> 3) & 7) * 1024 + d * 8 + (base & 7);
                    *(f16x4*)(vtp + off) = h;
                }
            }
    }
}

// ============================================================
// RMSNorm + RoPE -> panelized Q/K: [head][q-group][16 dchunks][64 q][8 d]
// grid (S_LEN, 2): y=0 Q, y=1 K
// ============================================================
__global__ __launch_bounds__(256) void norm_rope(const f16* __restrict__ preq,
                                                 const f16* __restrict__ prek,
                                                 const float* __restrict__ gq,
                                                 const float* __restrict__ gk,
                                                 const float* __restrict__ freqs,
                                                 f16* __restrict__ Qp,
                                                 f16* __restrict__ Kp) {
    int s = blockIdx.x, which = blockIdx.y;
    int t = threadIdx.x;
    const f16* pre = which ? prek : preq;
    const float* g = which ? gk : gq;
    f16* dst = which ? Kp : Qp;
    const f16* row = pre + (size_t)s * DIMSZ + t * 6;

    float v[6];
    float ss = 0.f;
#pragma unroll
    for (int i = 0; i < 3; i++) {
        f16x2 hp = *(const f16x2*)(row + 2 * i);
        v[2*i] = (float)hp[0]; v[2*i+1] = (float)hp[1];
        ss += v[2*i]*v[2*i] + v[2*i+1]*v[2*i+1];
    }
#pragma unroll
    for (int off = 32; off; off >>= 1) ss += __shfl_xor(ss, off);
    __shared__ float red[4];
    if ((t & 63) == 0) red[t >> 6] = ss;
    __syncthreads();
    float tot = red[0] + red[1] + red[2] + red[3];
    float rms = rsqrtf(tot * (1.0f / DIMSZ) + 1e-6f);

    int tpos = s / FRAME;
    int rem  = s % FRAME;
    int ypos = rem / 52;
    int xpos = s % 52;

#pragma unroll
    for (int u = 0; u < 3; u++) {
        int c = t * 6 + u * 2;
        int head = c >> 7;
        int d = c & 127;
        int j = d >> 1;
        int idx = (j < 22) ? tpos : ((j < 43) ? ypos : xpos);
        float ang = freqs[idx * 64 + j];
        float sn, cs;
        __sincosf(ang, &sn, &cs);
        float vr = v[u * 2]     * rms * g[c];
        float vi = v[u * 2 + 1] * rms * g[c + 1];
        f16* o = dst + (size_t)head * PANH + (size_t)(s >> 6) * 8192
               + (d >> 3) * 512 + (s & 63) * 8 + (d & 7);
        o[0] = (f16)(vr * cs - vi * sn);
        o[1] = (f16)(vr * sn + vi * cs);
    }
}

// ============================================================
// Attention partials. Block = 2 waves x 64 q (128 q-tile), head, chunk.
// Fine chunking: 2/4/6 chunks per tile by frame count -> grid (150, 12).
// 32x32x16 MFMA, S^T = K Q^T, O^T = V^T P^T.
// R5: V is NOT staged in LDS. The V panel (14.5 MB total) is L2/L3-
// resident and its layout is exactly the PV B-fragment layout, so each
// wave loads its 16 f16x8 V frags directly from global at iteration top
// (before the K-prefetch async16s, so the compiler's V wait is a counted
// vmcnt(8) that leaves the prefetch in flight). LDS drops 64->32 KB
// (K-only double buffer) -> 4 blocks/CU = 2 waves/SIMD with the two
// co-resident blocks at INDEPENDENT phases: the TLP that R1 (1 wave/
// SIMD, latency-bound at MfmaUtil 22%) was missing and R3's 4-wave
// lockstep couldn't deliver. K dbuf + counted vmcnt(24) kept. Body is
// R1's verified order; exp2-folded scale kept; setprio kept (two
// independent waves now give it something to arbitrate).
// ============================================================
__global__ __launch_bounds__(128, 2) void attn_part(const f16* __restrict__ Qp,
                                                    const f16* __restrict__ Kp,
                                                    const f16* __restrict__ Vp,
                                                    f16* __restrict__ Opart,
                                                    float* __restrict__ lpart) {
    int bx = blockIdx.x, head = blockIdx.y;
    int t, c, NC2;
    if (bx < 24)      { t = bx >> 1;             c = bx & 1;       NC2 = 2; }
    else if (bx < 72) { t = 12 + ((bx - 24) >> 2); c = (bx - 24) & 3; NC2 = 4; }
    else              { t = 24 + (bx - 72) / 6;  c = (bx - 72) % 6; NC2 = 6; }

    int qlast = min(t * 128 + 127, S_LEN - 1);
    int nfrm  = qlast / FRAME + 1;
    int kvend = nfrm * FRAME; if (kvend > S_LEN) kvend = S_LEN;
    int nG    = (kvend + 63) >> 6;
    int g0 = (c * nG) / NC2, g1 = ((c + 1) * nG) / NC2;
    int limB = ((t * 128) / FRAME + 1) * FRAME;

    int tid = threadIdx.x, lane = tid & 63, wv = tid >> 6;
    int l31 = lane & 31, lh = lane >> 5;
    int qw = t * 128 + wv * 64;

    __shared__ __align__(16) char smem[32768];   // K dbuf 2x16KB; epilogue reuse

    // Q B-frags from panelized global (coalesced), pre-scaled by
    // (1/sqrt(128)) * log2(e) so softmax uses exp2 directly
    const f16* Qg = Qp + ((size_t)head * NGRP + (qw >> 6)) * 8192;
    f16x8 bqf[2][8];
#pragma unroll
    for (int nt = 0; nt < 2; nt++)
#pragma unroll
        for (int ks = 0; ks < 8; ks++) {
            f16x8 vq = *(const f16x8*)(Qg + (2 * ks + lh) * 512 + (l31 + 32 * nt) * 8);
            bqf[nt][ks] = vq * (f16)0.12752044581f;   // 0.0883883 * 1.4426950
        }

    int lim[2];
#pragma unroll
    for (int nt = 0; nt < 2; nt++) {
        int q = qw + l31 + 32 * nt;
        lim[nt] = (q / FRAME + 1) * FRAME;
    }

    f32x16 oacc[4][2] = {};
    float lp[2] = {0.f, 0.f};

    int koff = lh * 1024 + l31 * 16;

    const f16* Kh = Kp + (size_t)head * NGRP * 8192;
    const f16* Vh = Vp + (size_t)head * NGRP * 8192;
    const f16* Vl = Vh + lh * 1024 + l31 * 8;    // per-lane V fragment base

    // ---- prologue: stage K group g0 into buffer 0 (8 async16 per wave) ----
#pragma unroll
    for (int i = 0; i < 8; i++) {
        int s = i * 2 + wv;
        async16(Kh + (size_t)g0 * 8192 + s * 512 + lane * 8,
                (char*)smem + s * 1024 + lane * 16);
    }

    int cur = 0;
    for (int g = g0; g < g1; g++) {
        int kb = g * 64;

        // ---- V frags for this group: direct global loads, issued FIRST so
        //      they are older than the K prefetch (counted V wait later) ----
        const f16* Vg = Vl + (size_t)g * 8192;
        f16x8 va[2][8];
#pragma unroll
        for (int kt = 0; kt < 2; kt++)
#pragma unroll
            for (int mt = 0; mt < 4; mt++)
#pragma unroll
                for (int ks = 0; ks < 2; ks++)
                    va[kt][mt * 2 + ks] = *(const f16x8*)(Vg + kt * 4096 + ks * 2048 + mt * 256);

        // ---- prefetch next K group into the other buffer, counted wait ----
        if (g + 1 < g1) {
            int nb = (cur ^ 1) << 14;
#pragma unroll
            for (int i = 0; i < 8; i++) {
                int s = i * 2 + wv;
                async16(Kh + (size_t)(g + 1) * 8192 + s * 512 + lane * 8,
                        (char*)smem + nb + s * 1024 + lane * 16);
            }
            // outstanding: 8 K_g (oldest) + 16 V_g + 8 K_{g+1} = 32.
            // vmcnt retires in-order -> vmcnt(24) waits exactly K_g.
            asm volatile("s_waitcnt vmcnt(24)" ::: "memory");
        } else {
            // outstanding: 8 K_g + 16 V_g -> vmcnt(16) waits K_g only.
            asm volatile("s_waitcnt vmcnt(16)" ::: "memory");
        }
        __builtin_amdgcn_s_barrier();

        const char* smc = (const char*)smem + (cur << 14);
        bool domask = (kb + 64 > limB);

#pragma unroll
        for (int kt = 0; kt < 2; kt++) {
            // ---- S^T = K Q^T ----
            f32x16 sc0 = {}, sc1 = {};
            __builtin_amdgcn_s_setprio(1);
#pragma unroll
            for (int h = 0; h < 2; h++) {
                f16x8 ka[4];
#pragma unroll
                for (int i = 0; i < 4; i++)
                    ka[i] = *(const f16x8*)(smc + koff + (h * 4 + i) * 2048 + kt * 512);
#pragma unroll
                for (int i = 0; i < 4; i++) {
                    sc0 = __builtin_amdgcn_mfma_f32_32x32x16_f16(ka[i], bqf[0][h*4+i], sc0, 0, 0, 0);
                    sc1 = __builtin_amdgcn_mfma_f32_32x32x16_f16(ka[i], bqf[1][h*4+i], sc1, 0, 0, 0);
                }
            }
            __builtin_amdgcn_s_setprio(0);

            // ---- mask + exp2 + pack ----
            int w[2][8];
            int keyb = kb + kt * 32 + 4 * lh;
#pragma unroll
            for (int nt = 0; nt < 2; nt++) {
#pragma unroll
                for (int p = 0; p < 8; p++) {
                    const int r0 = 2 * p;
                    float s0 = (nt == 0) ? sc0[r0]     : sc1[r0];
                    float s1 = (nt == 0) ? sc0[r0 + 1] : sc1[r0 + 1];
                    if (domask) {
                        int k0 = keyb + (r0 & 3) + 8 * (r0 >> 2);
                        if (k0     >= lim[nt]) s0 = -1e30f;
                        if (k0 + 1 >= lim[nt]) s1 = -1e30f;
                    }
                    float p0 = fexp2(s0), p1 = fexp2(s1);
                    lp[nt] += p0 + p1;
                    PkCast pk; pk.v = __builtin_amdgcn_cvt_pkrtz(p0, p1);
                    w[nt][p] = pk.i;
                }
            }

            // ---- C-layout -> P^T B-frags (cross-half dword exchange) ----
            f16x8 pb[2][2];
#pragma unroll
            for (int nt = 0; nt < 2; nt++)
#pragma unroll
                for (int ks = 0; ks < 2; ks++) {
                    FragCast fc;
#if __has_builtin(__builtin_amdgcn_permlane32_swap)
                    v2i r02 = __builtin_amdgcn_permlane32_swap(w[nt][4*ks+0], w[nt][4*ks+2], false, false);
                    v2i r13 = __builtin_amdgcn_permlane32_swap(w[nt][4*ks+1], w[nt][4*ks+3], false, false);
                    fc.w[0] = r02.x; fc.w[1] = r13.x; fc.w[2] = r02.y; fc.w[3] = r13.y;
#else
                    int w0 = w[nt][4*ks], w1 = w[nt][4*ks+1], w2 = w[nt][4*ks+2], w3 = w[nt][4*ks+3];
                    fc.w[0] = lh ? __shfl_xor(w2, 32) : w0;
                    fc.w[1] = lh ? __shfl_xor(w3, 32) : w1;
                    fc.w[2] = lh ? w2 : __shfl_xor(w0, 32);
                    fc.w[3] = lh ? w3 : __shfl_xor(w1, 32);
#endif
                    pb[nt][ks] = fc.v;
                }

            // ---- O^T += V^T P^T (V frags from registers, global-loaded) ----
            __builtin_amdgcn_s_setprio(1);
#pragma unroll
            for (int mt = 0; mt < 4; mt++)
#pragma unroll
                for (int ks = 0; ks < 2; ks++) {
                    f16x8 vaf = va[kt][mt * 2 + ks];
                    oacc[mt][0] = __builtin_amdgcn_mfma_f32_32x32x16_f16(vaf, pb[0][ks], oacc[mt][0], 0, 0, 0);
                    oacc[mt][1] = __builtin_amdgcn_mfma_f32_32x32x16_f16(vaf, pb[1][ks], oacc[mt][1], 0, 0, 0);
                }
            __builtin_amdgcn_s_setprio(0);
        }

        // all waves done reading K buf[cur] before next iter's stage overwrites
        __builtin_amdgcn_s_barrier();
        cur ^= 1;
    }

    // ---- l across lane-halves ----
    float lt[2], linv[2];
#pragma unroll
    for (int nt = 0; nt < 2; nt++) {
        float l = lp[nt] + __shfl_xor(lp[nt], 32);
        lt[nt] = l;
        linv[nt] = (l > 0.f) ? 1.f / l : 0.f;
    }

    // ---- epilogue through per-wave LDS (swizzled) -> coalesced global ----
    __syncthreads();
    char* ob = (char*)smem + wv * 16384;
#pragma unroll
    for (int mt = 0; mt < 4; mt++)
#pragma unroll
        for (int nt = 0; nt < 2; nt++) {
            int qloc = l31 + 32 * nt;
#pragma unroll
            for (int g4 = 0; g4 < 4; g4++) {
                f16x4 hv;
#pragma unroll
                for (int r = 0; r < 4; r++) hv[r] = (f16)(oacc[mt][nt][g4 * 4 + r] * linv[nt]);
                int c16 = g4 + 4 * mt;
                *(f16x4*)(ob + qloc * 256 + ((c16 ^ (qloc & 7)) << 4) + lh * 8) = hv;
            }
        }
    __syncthreads();

    // slot-compact partial layout: [head][slot=bx][128 q][128 d]
    size_t obase = ((size_t)(head * NSLOT + bx) * 128 + wv * 64) * HD;
#pragma unroll
    for (int a = 0; a < 4; a++)
#pragma unroll
        for (int b = 0; b < 4; b++) {
            int qloc = a * 16 + (lane >> 2);
            int c16  = (lane & 3) + 4 * b;
            f16x8 vv = *(const f16x8*)(ob + qloc * 256 + ((c16 ^ (qloc & 7)) << 4));
            *(f16x8*)(Opart + obase + (size_t)qloc * HD + c16 * 8) = vv;
        }

    if (lane < 32) {
        size_t lbase = (size_t)(head * NSLOT + bx) * 128 + wv * 64;
        lpart[lbase + l31]      = lt[0];
        lpart[lbase + l31 + 32] = lt[1];
    }
}

// ============================================================
// Combine chunk partials -> AO f16 [S][DIM]
// ============================================================
__global__ __launch_bounds__(256) void combine(const f16* __restrict__ Opart,
                                               const float* __restrict__ lpart,
                                               f16* __restrict__ AO) {
    int gid = blockIdx.x * 256 + threadIdx.x;
    if (gid >= S_LEN * NH * 16) return;
    int dc = gid & 15;
    int head = (gid >> 4) % NH;
    int q = gid / (NH * 16);
    int tt = q >> 7, qloc = q & 127;
    int base, nchunk;
    if (tt < 12)      { base = 2 * tt;             nchunk = 2; }
    else if (tt < 24) { base = 24 + 4 * (tt - 12); nchunk = 4; }
    else              { base = 72 + 6 * (tt - 24); nchunk = 6; }

    float sum[8] = {};
    float ls = 0.f;
    for (int c = 0; c < nchunk; c++) {
        size_t sbase = (size_t)(head * NSLOT + base + c) * 128 + qloc;
        float l = lpart[sbase];
        if (l > 0.f) {
            f16x8 o = *(const f16x8*)(Opart + sbase * HD + dc * 8);
#pragma unroll
            for (int j = 0; j < 8; j++) sum[j] += (float)o[j] * l;
            ls += l;
        }
    }
    float invl = 1.f / ls;
    f16x8 r;
#pragma unroll
    for (int j = 0; j < 8; j++) r[j] = (f16)(sum[j] * invl);
    *(f16x8*)(AO + (size_t)q * DIMSZ + head * HD + dc * 8) = r;
}

// ============================================================
// Output projection GEMM (m97 structure), f32 out
// ============================================================
__global__ __launch_bounds__(256) void gemm_lds(const f16* __restrict__ A,
                                                const f16* __restrict__ B,
                                                const float* __restrict__ bias,
                                                float* __restrict__ C) {
    __shared__ __align__(16) f16 Al[128 * 64];
    __shared__ __align__(16) f16 Bl[128 * 64];
    int tid = threadIdx.x;
    int lane = tid & 63, wv = tid >> 6;
    int l16 = lane & 15, quad = lane >> 4;
    int wr = (wv >> 1) * 64, wc = (wv & 1) * 64;
    int m0 = blockIdx.x * 128, n0 = blockIdx.y * 128;

    f32x4 acc[4][4] = {};

    for (int kb = 0; kb < DIMSZ; kb += 64) {
        __syncthreads();
#pragma unroll
        for (int j = 0; j < 4; j++) {
            int s = j * 256 + wv * 64 + lane;
            int r = s >> 3, cc = s & 7;
            const f16* src = A + (size_t)min(m0 + r, S_LEN - 1) * DIMSZ + kb + ((cc ^ (r & 7)) << 3);
            async16(src, (char*)Al + (j * 4096 + wv * 1024));
        }
#pragma unroll
        for (int j = 0; j < 4; j++) {
            int s = j * 256 + wv * 64 + lane;
            int r = s >> 3, cc = s & 7;
            const f16* src = B + (size_t)(n0 + r) * DIMSZ + kb + ((cc ^ (r & 7)) << 3);
            async16(src, (char*)Bl + (j * 4096 + wv * 1024));
        }
        __builtin_amdgcn_s_waitcnt(0x0f70);
        __syncthreads();

#pragma unroll
        for (int kc = 0; kc < 2; kc++) {
            f16x8 af[4], bf[4];
#pragma unroll
            for (int i = 0; i < 4; i++) {
                int ar = wr + i * 16 + l16;
                af[i] = *(const f16x8*)((const char*)Al + ar * 128 + (((kc * 4 + quad) ^ (ar & 7)) << 4));
                int br = wc + i * 16 + l16;
                bf[i] = *(const f16x8*)((const char*)Bl + br * 128 + (((kc * 4 + quad) ^ (br & 7)) << 4));
            }
#pragma unroll
            for (int mi = 0; mi < 4; mi++)
#pragma unroll
                for (int ni = 0; ni < 4; ni++)
                    acc[mi][ni] = __builtin_amdgcn_mfma_f32_16x16x32_f16(af[mi], bf[ni], acc[mi][ni], 0, 0, 0);
        }
    }

#pragma unroll
    for (int mi = 0; mi < 4; mi++)
#pragma unroll
        for (int ni = 0; ni < 4; ni++) {
            int col = n0 + wc + ni * 16 + l16;
            float bv = bias[col];
#pragma unroll
            for (int r = 0; r < 4; r++) {
                int row = m0 + wr + mi * 16 + quad * 4 + r;
                if (row < S_LEN) C[(size_t)row * DIMSZ + col] = acc[mi][ni][r] + bv;
            }
        }
}

// ============================================================
// host launch
// ============================================================
extern "C" void kernel_launch(void* const* d_in, const int* in_sizes, int n_in,
                              void* d_out, int out_size, void* d_ws, size_t ws_size,
                              hipStream_t stream) {
    const float* x     = (const float*)d_in[0];
    const float* freqs = (const float*)d_in[3];
    const float* Wq = (const float*)d_in[4];
    const float* bq = (const float*)d_in[5];
    const float* Wk = (const float*)d_in[6];
    const float* bk = (const float*)d_in[7];
    const float* Wv = (const float*)d_in[8];
    const float* bv = (const float*)d_in[9];
    const float* Wo = (const float*)d_in[10];
    const float* bo = (const float*)d_in[11];
    const float* gq = (const float*)d_in[12];
    const float* gk = (const float*)d_in[13];
    float* out = (float*)d_out;

    char* ws = (char*)d_ws;
    const size_t SZ_XH  = (size_t)S_LEN * DIMSZ * 2;     // 14,376,960
    const size_t SZ_W   = (size_t)DIMSZ * DIMSZ * 2;     //  4,718,592
    const size_t SZ_PAN = (size_t)NH * PANH * 2;         // 14,548,992
    const size_t SZ_OP  = (size_t)NH * NSLOT * 128 * HD * 2;  // 58,982,400

    size_t off = 0;
    f16* xh   = (f16*)(ws + off); off += SZ_XH;
    f16* wqh  = (f16*)(ws + off); off += 4 * SZ_W;       // wq,wk,wv,wo contiguous
    f16* wkh  = wqh + (size_t)DIMSZ * DIMSZ;
    f16* wvh  = wkh + (size_t)DIMSZ * DIMSZ;
    f16* woh  = wvh + (size_t)DIMSZ * DIMSZ;
    f16* Qpan = (f16*)(ws + off); off += SZ_PAN;
    f16* Kpan = (f16*)(ws + off); off += SZ_PAN;
    f16* Vpan = (f16*)(ws + off); off += SZ_PAN;
    // AO aliases Qpan: Qpan is dead after attn_part; combine writes AO
    // strictly after (stream-ordered). Keeps total ws at ~137 MB.
    f16* AO   = Qpan;
    // union: {preq, prek} (f16) before attention | {Opart, lpart} after
    f16*   preq  = (f16*)(ws + off);
    f16*   prek  = preq + (size_t)S_LEN * DIMSZ;
    f16*   Opart = (f16*)(ws + off);
    float* lpart = (float*)(ws + off + SZ_OP);

    cast_all<<<dim3(7020, 5), 256, 0, stream>>>(x, Wq, Wk, Wv, Wo, xh, wqh);

    gemm_qkv<<<dim3(37, 12, 3), 256, 0, stream>>>(xh, wqh, wkh, wvh, bq, bk, bv,
                                                  preq, prek, Vpan);

    norm_rope<<<dim3(S_LEN, 2), 256, 0, stream>>>(preq, prek, gq, gk, freqs, Qpan, Kpan);

    attn_part<<<dim3(NSLOT, 12), 128, 0, stream>>>(Qpan, Kpan, Vpan, Opart, lpart);
    combine<<<(S_LEN * NH * 16 + 255) / 256, 256, 0, stream>>>(Opart, lpart, AO);

    gemm_lds<<<dim3(37, 12), 256, 0, stream>>>(AO, woh, bo, out);
}

// Round 6
// 588.219 us; speedup vs baseline: 1.2394x; 1.2394x over previous
//
#include <hip/hip_runtime.h>
#include <hip/hip_bf16.h>
#include <math.h>
#include <stdint.h>

// ---- problem constants ----
#define S_LEN 4680
#define DIMSZ 1536
#define NH    12
#define HD    128
#define FRAME 1560
#define NGRP  74        // padded 64-key/-q groups (74*64 = 4736)
#define PANH  (NGRP * 8192)   // f16 elems per head in a panelized tensor
#define NSLOT 150       // (q-tile, chunk) slots per head: 12*2 + 12*4 + 13*6

typedef _Float16 f16;
typedef _Float16 f16x8 __attribute__((ext_vector_type(8)));
typedef _Float16 f16x4 __attribute__((ext_vector_type(4)));
typedef _Float16 f16x2 __attribute__((ext_vector_type(2)));
typedef __fp16   fp16x2 __attribute__((ext_vector_type(2)));
typedef float    f32x4  __attribute__((ext_vector_type(4)));
typedef float    f32x16 __attribute__((ext_vector_type(16)));
typedef int      v2i    __attribute__((ext_vector_type(2)));

__device__ __forceinline__ void async16(const void* g, void* l) {
    __builtin_amdgcn_global_load_lds((const __attribute__((address_space(1))) void*)g,
                                     (__attribute__((address_space(3))) void*)l, 16, 0, 0);
}

__device__ __forceinline__ float fexp2(float x) {
#if __has_builtin(__builtin_amdgcn_exp2f)
    return __builtin_amdgcn_exp2f(x);
#else
    return exp2f(x);
#endif
}

union PkCast { fp16x2 v; int i; };
union FragCast { int w[4]; f16x8 v; };

// ============================================================
// all f32->f16 casts in one dispatch: y=0 x, y=1..4 weights
// ============================================================
__global__ __launch_bounds__(256) void cast_all(const float* __restrict__ x,
                                                const float* __restrict__ wq,
                                                const float* __restrict__ wk,
                                                const float* __restrict__ wv,
                                                const float* __restrict__ wo,
                                                f16* __restrict__ xh,
                                                f16* __restrict__ wh) {
    int y = blockIdx.y;
    int i = blockIdx.x * 256 + threadIdx.x;
    if (y == 0) {
        if (i < (S_LEN * DIMSZ) / 4) {
            float4 v = ((const float4*)x)[i];
            f16x4 h; h[0]=(f16)v.x; h[1]=(f16)v.y; h[2]=(f16)v.z; h[3]=(f16)v.w;
            ((f16x4*)xh)[i] = h;
        }
    } else {
        const int nW4 = (DIMSZ * DIMSZ) / 4;
        if (i < nW4) {
            const float* src = (y==1)?wq:(y==2)?wk:(y==3)?wv:wo;
            float4 v = ((const float4*)src)[i];
            f16x4 h; h[0]=(f16)v.x; h[1]=(f16)v.y; h[2]=(f16)v.z; h[3]=(f16)v.w;
            ((f16x4*)wh)[(size_t)(y-1)*nW4 + i] = h;
        }
    }
}

// ============================================================
// Fused QKV GEMM (m97 structure), grid (37,12,3).
// z=0/1: pre-norm Q/K, f16 row-major. z=2: V, f16 panelized Vt.
// Vt panels: [head][key-group][8 kchunks][128 d][8 keys]
// ============================================================
__global__ __launch_bounds__(256) void gemm_qkv(const f16* __restrict__ A,
                                                const f16* __restrict__ Bq,
                                                const f16* __restrict__ Bk,
                                                const f16* __restrict__ Bv,
                                                const float* __restrict__ bq,
                                                const float* __restrict__ bk,
                                                const float* __restrict__ bv,
                                                f16* __restrict__ preq,
                                                f16* __restrict__ prek,
                                                f16* __restrict__ vtp) {
    int z = blockIdx.z;
    const f16* B = (z==0) ? Bq : (z==1) ? Bk : Bv;
    const float* bias = (z==0) ? bq : (z==1) ? bk : bv;

    __shared__ __align__(16) f16 Al[128 * 64];
    __shared__ __align__(16) f16 Bl[128 * 64];
    int tid = threadIdx.x;
    int lane = tid & 63, wv = tid >> 6;
    int l16 = lane & 15, quad = lane >> 4;
    int wr = (wv >> 1) * 64, wc = (wv & 1) * 64;
    int m0 = blockIdx.x * 128, n0 = blockIdx.y * 128;

    f32x4 acc[4][4] = {};

    for (int kb = 0; kb < DIMSZ; kb += 64) {
        __syncthreads();
#pragma unroll
        for (int j = 0; j < 4; j++) {
            int s = j * 256 + wv * 64 + lane;
            int r = s >> 3, cc = s & 7;
            const f16* src = A + (size_t)min(m0 + r, S_LEN - 1) * DIMSZ + kb + ((cc ^ (r & 7)) << 3);
            async16(src, (char*)Al + (j * 4096 + wv * 1024));
        }
#pragma unroll
        for (int j = 0; j < 4; j++) {
            int s = j * 256 + wv * 64 + lane;
            int r = s >> 3, cc = s & 7;
            const f16* src = B + (size_t)(n0 + r) * DIMSZ + kb + ((cc ^ (r & 7)) << 3);
            async16(src, (char*)Bl + (j * 4096 + wv * 1024));
        }
        __builtin_amdgcn_s_waitcnt(0x0f70);
        __syncthreads();

#pragma unroll
        for (int kc = 0; kc < 2; kc++) {
            f16x8 af[4], bf[4];
#pragma unroll
            for (int i = 0; i < 4; i++) {
                int ar = wr + i * 16 + l16;
                af[i] = *(const f16x8*)((const char*)Al + ar * 128 + (((kc * 4 + quad) ^ (ar & 7)) << 4));
                int br = wc + i * 16 + l16;
                bf[i] = *(const f16x8*)((const char*)Bl + br * 128 + (((kc * 4 + quad) ^ (br & 7)) << 4));
            }
#pragma unroll
            for (int mi = 0; mi < 4; mi++)
#pragma unroll
                for (int ni = 0; ni < 4; ni++)
                    acc[mi][ni] = __builtin_amdgcn_mfma_f32_16x16x32_f16(af[mi], bf[ni], acc[mi][ni], 0, 0, 0);
        }
    }

    if (z < 2) {
        f16* C = (z == 0) ? preq : prek;
#pragma unroll
        for (int mi = 0; mi < 4; mi++)
#pragma unroll
            for (int ni = 0; ni < 4; ni++) {
                int col = n0 + wc + ni * 16 + l16;
                float bv_ = bias[col];
#pragma unroll
                for (int r = 0; r < 4; r++) {
                    int row = m0 + wr + mi * 16 + quad * 4 + r;
                    if (row < S_LEN) C[(size_t)row * DIMSZ + col] = (f16)(acc[mi][ni][r] + bv_);
                }
            }
    } else {
#pragma unroll
        for (int mi = 0; mi < 4; mi++)
#pragma unroll
            for (int ni = 0; ni < 4; ni++) {
                int col  = n0 + wc + ni * 16 + l16;
                int vhead = col >> 7, d = col & 127;
                int base = m0 + wr + mi * 16 + quad * 4;   // 4 consecutive keys
                if (base < S_LEN) {
                    float bv_ = bias[col];
                    f16x4 h;
#pragma unroll
                    for (int r = 0; r < 4; r++) h[r] = (f16)(acc[mi][ni][r] + bv_);
                    size_t off = (size_t)vhead * PANH + (size_t)(base >> 6) * 8192
                               + ((base >> 3) & 7) * 1024 + d * 8 + (base & 7);
                    *(f16x4*)(vtp + off) = h;
                }
            }
    }
}

// ============================================================
// RMSNorm + RoPE -> panelized Q/K: [head][q-group][16 dchunks][64 q][8 d]
// grid (S_LEN, 2): y=0 Q, y=1 K
// ============================================================
__global__ __launch_bounds__(256) void norm_rope(const f16* __restrict__ preq,
                                                 const f16* __restrict__ prek,
                                                 const float* __restrict__ gq,
                                                 const float* __restrict__ gk,
                                                 const float* __restrict__ freqs,
                                                 f16* __restrict__ Qp,
                                                 f16* __restrict__ Kp) {
    int s = blockIdx.x, which = blockIdx.y;
    int t = threadIdx.x;
    const f16* pre = which ? prek : preq;
    const float* g = which ? gk : gq;
    f16* dst = which ? Kp : Qp;
    const f16* row = pre + (size_t)s * DIMSZ + t * 6;

    float v[6];
    float ss = 0.f;
#pragma unroll
    for (int i = 0; i < 3; i++) {
        f16x2 hp = *(const f16x2*)(row + 2 * i);
        v[2*i] = (float)hp[0]; v[2*i+1] = (float)hp[1];
        ss += v[2*i]*v[2*i] + v[2*i+1]*v[2*i+1];
    }
#pragma unroll
    for (int off = 32; off; off >>= 1) ss += __shfl_xor(ss, off);
    __shared__ float red[4];
    if ((t & 63) == 0) red[t >> 6] = ss;
    __syncthreads();
    float tot = red[0] + red[1] + red[2] + red[3];
    float rms = rsqrtf(tot * (1.0f / DIMSZ) + 1e-6f);

    int tpos = s / FRAME;
    int rem  = s % FRAME;
    int ypos = rem / 52;
    int xpos = s % 52;

#pragma unroll
    for (int u = 0; u < 3; u++) {
        int c = t * 6 + u * 2;
        int head = c >> 7;
        int d = c & 127;
        int j = d >> 1;
        int idx = (j < 22) ? tpos : ((j < 43) ? ypos : xpos);
        float ang = freqs[idx * 64 + j];
        float sn, cs;
        __sincosf(ang, &sn, &cs);
        float vr = v[u * 2]     * rms * g[c];
        float vi = v[u * 2 + 1] * rms * g[c + 1];
        f16* o = dst + (size_t)head * PANH + (size_t)(s >> 6) * 8192
               + (d >> 3) * 512 + (s & 63) * 8 + (d & 7);
        o[0] = (f16)(vr * cs - vi * sn);
        o[1] = (f16)(vr * sn + vi * cs);
    }
}

// ============================================================
// Attention partials. Block = 2 waves x 64 q (128 q-tile), head, chunk.
// Fine chunking: 2/4/6 chunks per tile by frame count -> grid (150, 12).
// 32x32x16 MFMA, S^T = K Q^T, O^T = V^T P^T.
// R6: 48KB LDS = K dbuf (2x16KB @0) + V single buffer (16KB @32768)
// -> 3 blocks/CU (was 2 at 64KB) = 1.5 waves/SIMD of INDEPENDENT-phase
// blocks. Both K and V stay async16-staged (R5 proved per-wave global V
// loads thrash L2: FETCH 96->713MB). Per group: issue V(g) (protected
// by prev end barrier), issue K(g+1) prefetch, counted vmcnt(16) for
// K(g) only, barrier; QK(kt0)+softmax; counted vmcnt(8) retires V(g)
// with K(g+1) still in flight + barrier; PV(kt0); kt1 full; end barrier.
// V latency hides under QK+softmax; K prefetch never drained mid-loop.
// ============================================================
__global__ __launch_bounds__(128, 2) void attn_part(const f16* __restrict__ Qp,
                                                    const f16* __restrict__ Kp,
                                                    const f16* __restrict__ Vp,
                                                    f16* __restrict__ Opart,
                                                    float* __restrict__ lpart) {
    int bx = blockIdx.x, head = blockIdx.y;
    int t, c, NC2;
    if (bx < 24)      { t = bx >> 1;             c = bx & 1;       NC2 = 2; }
    else if (bx < 72) { t = 12 + ((bx - 24) >> 2); c = (bx - 24) & 3; NC2 = 4; }
    else              { t = 24 + (bx - 72) / 6;  c = (bx - 72) % 6; NC2 = 6; }

    int qlast = min(t * 128 + 127, S_LEN - 1);
    int nfrm  = qlast / FRAME + 1;
    int kvend = nfrm * FRAME; if (kvend > S_LEN) kvend = S_LEN;
    int nG    = (kvend + 63) >> 6;
    int g0 = (c * nG) / NC2, g1 = ((c + 1) * nG) / NC2;
    int limB = ((t * 128) / FRAME + 1) * FRAME;

    int tid = threadIdx.x, lane = tid & 63, wv = tid >> 6;
    int l31 = lane & 31, lh = lane >> 5;
    int qw = t * 128 + wv * 64;

    __shared__ __align__(16) char smem[49152];   // K dbuf @0/@16384, V @32768

    // Q B-frags from panelized global (coalesced), pre-scaled by
    // (1/sqrt(128)) * log2(e) so softmax uses exp2 directly
    const f16* Qg = Qp + ((size_t)head * NGRP + (qw >> 6)) * 8192;
    f16x8 bqf[2][8];
#pragma unroll
    for (int nt = 0; nt < 2; nt++)
#pragma unroll
        for (int ks = 0; ks < 8; ks++) {
            f16x8 vq = *(const f16x8*)(Qg + (2 * ks + lh) * 512 + (l31 + 32 * nt) * 8);
            bqf[nt][ks] = vq * (f16)0.12752044581f;   // 0.0883883 * 1.4426950
        }

    int lim[2];
#pragma unroll
    for (int nt = 0; nt < 2; nt++) {
        int q = qw + l31 + 32 * nt;
        lim[nt] = (q / FRAME + 1) * FRAME;
    }

    f32x16 oacc[4][2] = {};
    float lp[2] = {0.f, 0.f};

    int koff = lh * 1024 + l31 * 16;
    int voff = 32768 + lh * 2048 + l31 * 16;

    const f16* Kh = Kp + (size_t)head * NGRP * 8192;
    const f16* Vh = Vp + (size_t)head * NGRP * 8192;

    // ---- prologue: stage K group g0 into buffer 0 (8 async16 per wave) ----
#pragma unroll
    for (int i = 0; i < 8; i++) {
        int s = i * 2 + wv;
        async16(Kh + (size_t)g0 * 8192 + s * 512 + lane * 8,
                (char*)smem + s * 1024 + lane * 16);
    }

    int cur = 0;
    for (int g = g0; g < g1; g++) {
        int kb = g * 64;

        // ---- V(g) into single V buffer (prev end-barrier protects reads) ----
#pragma unroll
        for (int i = 0; i < 8; i++) {
            int s = i * 2 + wv;
            async16(Vh + (size_t)g * 8192 + s * 512 + lane * 8,
                    (char*)smem + 32768 + s * 1024 + lane * 16);
        }

        // ---- prefetch next K group into the other buffer ----
        if (g + 1 < g1) {
            int nb = (cur ^ 1) << 14;
#pragma unroll
            for (int i = 0; i < 8; i++) {
                int s = i * 2 + wv;
                async16(Kh + (size_t)(g + 1) * 8192 + s * 512 + lane * 8,
                        (char*)smem + nb + s * 1024 + lane * 16);
            }
            // per-wave outstanding: K(g) 8 (oldest) + V(g) 8 + K(g+1) 8.
            // vmcnt retires in-order -> vmcnt(16) waits exactly K(g).
            asm volatile("s_waitcnt vmcnt(16)" ::: "memory");
        } else {
            // outstanding: K(g) 8 + V(g) 8 -> vmcnt(8) waits K(g) only.
            asm volatile("s_waitcnt vmcnt(8)" ::: "memory");
        }
        __builtin_amdgcn_s_barrier();            // B1: K(g) valid

        const char* smc = (const char*)smem + (cur << 14);
        bool domask = (kb + 64 > limB);

#pragma unroll
        for (int kt = 0; kt < 2; kt++) {
            // ---- S^T = K Q^T ----
            f32x16 sc0 = {}, sc1 = {};
            __builtin_amdgcn_s_setprio(1);
#pragma unroll
            for (int h = 0; h < 2; h++) {
                f16x8 ka[4];
#pragma unroll
                for (int i = 0; i < 4; i++)
                    ka[i] = *(const f16x8*)(smc + koff + (h * 4 + i) * 2048 + kt * 512);
#pragma unroll
                for (int i = 0; i < 4; i++) {
                    sc0 = __builtin_amdgcn_mfma_f32_32x32x16_f16(ka[i], bqf[0][h*4+i], sc0, 0, 0, 0);
                    sc1 = __builtin_amdgcn_mfma_f32_32x32x16_f16(ka[i], bqf[1][h*4+i], sc1, 0, 0, 0);
                }
            }
            __builtin_amdgcn_s_setprio(0);

            // ---- mask + exp2 + pack ----
            int w[2][8];
            int keyb = kb + kt * 32 + 4 * lh;
#pragma unroll
            for (int nt = 0; nt < 2; nt++) {
#pragma unroll
                for (int p = 0; p < 8; p++) {
                    const int r0 = 2 * p;
                    float s0 = (nt == 0) ? sc0[r0]     : sc1[r0];
                    float s1 = (nt == 0) ? sc0[r0 + 1] : sc1[r0 + 1];
                    if (domask) {
                        int k0 = keyb + (r0 & 3) + 8 * (r0 >> 2);
                        if (k0     >= lim[nt]) s0 = -1e30f;
                        if (k0 + 1 >= lim[nt]) s1 = -1e30f;
                    }
                    float p0 = fexp2(s0), p1 = fexp2(s1);
                    lp[nt] += p0 + p1;
                    PkCast pk; pk.v = __builtin_amdgcn_cvt_pkrtz(p0, p1);
                    w[nt][p] = pk.i;
                }
            }

            // ---- C-layout -> P^T B-frags (cross-half dword exchange) ----
            f16x8 pb[2][2];
#pragma unroll
            for (int nt = 0; nt < 2; nt++)
#pragma unroll
                for (int ks = 0; ks < 2; ks++) {
                    FragCast fc;
#if __has_builtin(__builtin_amdgcn_permlane32_swap)
                    v2i r02 = __builtin_amdgcn_permlane32_swap(w[nt][4*ks+0], w[nt][4*ks+2], false, false);
                    v2i r13 = __builtin_amdgcn_permlane32_swap(w[nt][4*ks+1], w[nt][4*ks+3], false, false);
                    fc.w[0] = r02.x; fc.w[1] = r13.x; fc.w[2] = r02.y; fc.w[3] = r13.y;
#else
                    int w0 = w[nt][4*ks], w1 = w[nt][4*ks+1], w2 = w[nt][4*ks+2], w3 = w[nt][4*ks+3];
                    fc.w[0] = lh ? __shfl_xor(w2, 32) : w0;
                    fc.w[1] = lh ? __shfl_xor(w3, 32) : w1;
                    fc.w[2] = lh ? w2 : __shfl_xor(w0, 32);
                    fc.w[3] = lh ? w3 : __shfl_xor(w1, 32);
#endif
                    pb[nt][ks] = fc.v;
                }

            // ---- V-ready gate before first PV: counted wait retires V(g),
            //      K(g+1) prefetch stays in flight; barrier covers the
            //      cross-wave slot split of the async16 staging ----
            if (kt == 0) {
                if (g + 1 < g1) asm volatile("s_waitcnt vmcnt(8)" ::: "memory");
                else            asm volatile("s_waitcnt vmcnt(0)" ::: "memory");
                __builtin_amdgcn_s_barrier();    // B2: V(g) valid
            }

            // ---- O^T += V^T P^T ----
            __builtin_amdgcn_s_setprio(1);
#pragma unroll
            for (int mt = 0; mt < 4; mt++)
#pragma unroll
                for (int ks = 0; ks < 2; ks++) {
                    f16x8 va = *(const f16x8*)((const char*)smem + voff + kt * 8192 + ks * 4096 + mt * 512);
                    oacc[mt][0] = __builtin_amdgcn_mfma_f32_32x32x16_f16(va, pb[0][ks], oacc[mt][0], 0, 0, 0);
                    oacc[mt][1] = __builtin_amdgcn_mfma_f32_32x32x16_f16(va, pb[1][ks], oacc[mt][1], 0, 0, 0);
                }
            __builtin_amdgcn_s_setprio(0);
        }

        // B3: all waves done with K buf cur + V buffer before next iter's
        // staging overwrites them
        __builtin_amdgcn_s_barrier();
        cur ^= 1;
    }

    // ---- l across lane-halves ----
    float lt[2], linv[2];
#pragma unroll
    for (int nt = 0; nt < 2; nt++) {
        float l = lp[nt] + __shfl_xor(lp[nt], 32);
        lt[nt] = l;
        linv[nt] = (l > 0.f) ? 1.f / l : 0.f;
    }

    // ---- epilogue through per-wave LDS (swizzled) -> coalesced global ----
    __syncthreads();
    char* ob = (char*)smem + wv * 16384;
#pragma unroll
    for (int mt = 0; mt < 4; mt++)
#pragma unroll
        for (int nt = 0; nt < 2; nt++) {
            int qloc = l31 + 32 * nt;
#pragma unroll
            for (int g4 = 0; g4 < 4; g4++) {
                f16x4 hv;
#pragma unroll
                for (int r = 0; r < 4; r++) hv[r] = (f16)(oacc[mt][nt][g4 * 4 + r] * linv[nt]);
                int c16 = g4 + 4 * mt;
                *(f16x4*)(ob + qloc * 256 + ((c16 ^ (qloc & 7)) << 4) + lh * 8) = hv;
            }
        }
    __syncthreads();

    // slot-compact partial layout: [head][slot=bx][128 q][128 d]
    size_t obase = ((size_t)(head * NSLOT + bx) * 128 + wv * 64) * HD;
#pragma unroll
    for (int a = 0; a < 4; a++)
#pragma unroll
        for (int b = 0; b < 4; b++) {
            int qloc = a * 16 + (lane >> 2);
            int c16  = (lane & 3) + 4 * b;
            f16x8 vv = *(const f16x8*)(ob + qloc * 256 + ((c16 ^ (qloc & 7)) << 4));
            *(f16x8*)(Opart + obase + (size_t)qloc * HD + c16 * 8) = vv;
        }

    if (lane < 32) {
        size_t lbase = (size_t)(head * NSLOT + bx) * 128 + wv * 64;
        lpart[lbase + l31]      = lt[0];
        lpart[lbase + l31 + 32] = lt[1];
    }
}

// ============================================================
// Combine chunk partials -> AO f16 [S][DIM]
// ============================================================
__global__ __launch_bounds__(256) void combine(const f16* __restrict__ Opart,
                                               const float* __restrict__ lpart,
                                               f16* __restrict__ AO) {
    int gid = blockIdx.x * 256 + threadIdx.x;
    if (gid >= S_LEN * NH * 16) return;
    int dc = gid & 15;
    int head = (gid >> 4) % NH;
    int q = gid / (NH * 16);
    int tt = q >> 7, qloc = q & 127;
    int base, nchunk;
    if (tt < 12)      { base = 2 * tt;             nchunk = 2; }
    else if (tt < 24) { base = 24 + 4 * (tt - 12); nchunk = 4; }
    else              { base = 72 + 6 * (tt - 24); nchunk = 6; }

    float sum[8] = {};
    float ls = 0.f;
    for (int c = 0; c < nchunk; c++) {
        size_t sbase = (size_t)(head * NSLOT + base + c) * 128 + qloc;
        float l = lpart[sbase];
        if (l > 0.f) {
            f16x8 o = *(const f16x8*)(Opart + sbase * HD + dc * 8);
#pragma unroll
            for (int j = 0; j < 8; j++) sum[j] += (float)o[j] * l;
            ls += l;
        }
    }
    float invl = 1.f / ls;
    f16x8 r;
#pragma unroll
    for (int j = 0; j < 8; j++) r[j] = (f16)(sum[j] * invl);
    *(f16x8*)(AO + (size_t)q * DIMSZ + head * HD + dc * 8) = r;
}

// ============================================================
// Output projection GEMM (m97 structure), f32 out
// ============================================================
__global__ __launch_bounds__(256) void gemm_lds(const f16* __restrict__ A,
                                                const f16* __restrict__ B,
                                                const float* __restrict__ bias,
                                                float* __restrict__ C) {
    __shared__ __align__(16) f16 Al[128 * 64];
    __shared__ __align__(16) f16 Bl[128 * 64];
    int tid = threadIdx.x;
    int lane = tid & 63, wv = tid >> 6;
    int l16 = lane & 15, quad = lane >> 4;
    int wr = (wv >> 1) * 64, wc = (wv & 1) * 64;
    int m0 = blockIdx.x * 128, n0 = blockIdx.y * 128;

    f32x4 acc[4][4] = {};

    for (int kb = 0; kb < DIMSZ; kb += 64) {
        __syncthreads();
#pragma unroll
        for (int j = 0; j < 4; j++) {
            int s = j * 256 + wv * 64 + lane;
            int r = s >> 3, cc = s & 7;
            const f16* src = A + (size_t)min(m0 + r, S_LEN - 1) * DIMSZ + kb + ((cc ^ (r & 7)) << 3);
            async16(src, (char*)Al + (j * 4096 + wv * 1024));
        }
#pragma unroll
        for (int j = 0; j < 4; j++) {
            int s = j * 256 + wv * 64 + lane;
            int r = s >> 3, cc = s & 7;
            const f16* src = B + (size_t)(n0 + r) * DIMSZ + kb + ((cc ^ (r & 7)) << 3);
            async16(src, (char*)Bl + (j * 4096 + wv * 1024));
        }
        __builtin_amdgcn_s_waitcnt(0x0f70);
        __syncthreads();

#pragma unroll
        for (int kc = 0; kc < 2; kc++) {
            f16x8 af[4], bf[4];
#pragma unroll
            for (int i = 0; i < 4; i++) {
                int ar = wr + i * 16 + l16;
                af[i] = *(const f16x8*)((const char*)Al + ar * 128 + (((kc * 4 + quad) ^ (ar & 7)) << 4));
                int br = wc + i * 16 + l16;
                bf[i] = *(const f16x8*)((const char*)Bl + br * 128 + (((kc * 4 + quad) ^ (br & 7)) << 4));
            }
#pragma unroll
            for (int mi = 0; mi < 4; mi++)
#pragma unroll
                for (int ni = 0; ni < 4; ni++)
                    acc[mi][ni] = __builtin_amdgcn_mfma_f32_16x16x32_f16(af[mi], bf[ni], acc[mi][ni], 0, 0, 0);
        }
    }

#pragma unroll
    for (int mi = 0; mi < 4; mi++)
#pragma unroll
        for (int ni = 0; ni < 4; ni++) {
            int col = n0 + wc + ni * 16 + l16;
            float bv = bias[col];
#pragma unroll
            for (int r = 0; r < 4; r++) {
                int row = m0 + wr + mi * 16 + quad * 4 + r;
                if (row < S_LEN) C[(size_t)row * DIMSZ + col] = acc[mi][ni][r] + bv;
            }
        }
}

// ============================================================
// host launch
// ============================================================
extern "C" void kernel_launch(void* const* d_in, const int* in_sizes, int n_in,
                              void* d_out, int out_size, void* d_ws, size_t ws_size,
                              hipStream_t stream) {
    const float* x     = (const float*)d_in[0];
    const float* freqs = (const float*)d_in[3];
    const float* Wq = (const float*)d_in[4];
    const float* bq = (const float*)d_in[5];
    const float* Wk = (const float*)d_in[6];
    const float* bk = (const float*)d_in[7];
    const float* Wv = (const float*)d_in[8];
    const float* bv = (const float*)d_in[9];
    const float* Wo = (const float*)d_in[10];
    const float* bo = (const float*)d_in[11];
    const float* gq = (const float*)d_in[12];
    const float* gk = (const float*)d_in[13];
    float* out = (float*)d_out;

    char* ws = (char*)d_ws;
    const size_t SZ_XH  = (size_t)S_LEN * DIMSZ * 2;     // 14,376,960
    const size_t SZ_W   = (size_t)DIMSZ * DIMSZ * 2;     //  4,718,592
    const size_t SZ_PAN = (size_t)NH * PANH * 2;         // 14,548,992
    const size_t SZ_OP  = (size_t)NH * NSLOT * 128 * HD * 2;  // 58,982,400

    size_t off = 0;
    f16* xh   = (f16*)(ws + off); off += SZ_XH;
    f16* wqh  = (f16*)(ws + off); off += 4 * SZ_W;       // wq,wk,wv,wo contiguous
    f16* wkh  = wqh + (size_t)DIMSZ * DIMSZ;
    f16* wvh  = wkh + (size_t)DIMSZ * DIMSZ;
    f16* woh  = wvh + (size_t)DIMSZ * DIMSZ;
    f16* Qpan = (f16*)(ws + off); off += SZ_PAN;
    f16* Kpan = (f16*)(ws + off); off += SZ_PAN;
    f16* Vpan = (f16*)(ws + off); off += SZ_PAN;
    // AO aliases Qpan: Qpan is dead after attn_part; combine writes AO
    // strictly after (stream-ordered). Keeps total ws at ~137 MB.
    f16* AO   = Qpan;
    // union: {preq, prek} (f16) before attention | {Opart, lpart} after
    f16*   preq  = (f16*)(ws + off);
    f16*   prek  = preq + (size_t)S_LEN * DIMSZ;
    f16*   Opart = (f16*)(ws + off);
    float* lpart = (float*)(ws + off + SZ_OP);

    cast_all<<<dim3(7020, 5), 256, 0, stream>>>(x, Wq, Wk, Wv, Wo, xh, wqh);

    gemm_qkv<<<dim3(37, 12, 3), 256, 0, stream>>>(xh, wqh, wkh, wvh, bq, bk, bv,
                                                  preq, prek, Vpan);

    norm_rope<<<dim3(S_LEN, 2), 256, 0, stream>>>(preq, prek, gq, gk, freqs, Qpan, Kpan);

    attn_part<<<dim3(NSLOT, 12), 128, 0, stream>>>(Qpan, Kpan, Vpan, Opart, lpart);
    combine<<<(S_LEN * NH * 16 + 255) / 256, 256, 0, stream>>>(Opart, lpart, AO);

    gemm_lds<<<dim3(37, 12), 256, 0, stream>>>(AO, woh, bo, out);
}

// Round 7
// 493.893 us; speedup vs baseline: 1.4761x; 1.1910x over previous
//
#include <hip/hip_runtime.h>
#include <hip/hip_bf16.h>
#include <math.h>
#include <stdint.h>

// ---- problem constants ----
#define S_LEN 4680
#define DIMSZ 1536
#define NH    12
#define HD    128
#define FRAME 1560
#define NGRP  74        // padded 64-key/-q groups (74*64 = 4736)
#define PANH  (NGRP * 8192)   // f16 elems per head in a panelized tensor
#define NSLOT 150       // (q-tile, chunk) slots per head: 12*2 + 12*4 + 13*6

typedef _Float16 f16;
typedef _Float16 f16x8 __attribute__((ext_vector_type(8)));
typedef _Float16 f16x4 __attribute__((ext_vector_type(4)));
typedef _Float16 f16x2 __attribute__((ext_vector_type(2)));
typedef __fp16   fp16x2 __attribute__((ext_vector_type(2)));
typedef float    f32x4  __attribute__((ext_vector_type(4)));
typedef float    f32x16 __attribute__((ext_vector_type(16)));
typedef int      v2i    __attribute__((ext_vector_type(2)));

__device__ __forceinline__ void async16(const void* g, void* l) {
    __builtin_amdgcn_global_load_lds((const __attribute__((address_space(1))) void*)g,
                                     (__attribute__((address_space(3))) void*)l, 16, 0, 0);
}

__device__ __forceinline__ float fexp2(float x) {
#if __has_builtin(__builtin_amdgcn_exp2f)
    return __builtin_amdgcn_exp2f(x);
#else
    return exp2f(x);
#endif
}

union PkCast { fp16x2 v; int i; };
union FragCast { int w[4]; f16x8 v; };

// ============================================================
// all f32->f16 casts in one dispatch: y=0 x, y=1..4 weights
// ============================================================
__global__ __launch_bounds__(256) void cast_all(const float* __restrict__ x,
                                                const float* __restrict__ wq,
                                                const float* __restrict__ wk,
                                                const float* __restrict__ wv,
                                                const float* __restrict__ wo,
                                                f16* __restrict__ xh,
                                                f16* __restrict__ wh) {
    int y = blockIdx.y;
    int i = blockIdx.x * 256 + threadIdx.x;
    if (y == 0) {
        if (i < (S_LEN * DIMSZ) / 4) {
            float4 v = ((const float4*)x)[i];
            f16x4 h; h[0]=(f16)v.x; h[1]=(f16)v.y; h[2]=(f16)v.z; h[3]=(f16)v.w;
            ((f16x4*)xh)[i] = h;
        }
    } else {
        const int nW4 = (DIMSZ * DIMSZ) / 4;
        if (i < nW4) {
            const float* src = (y==1)?wq:(y==2)?wk:(y==3)?wv:wo;
            float4 v = ((const float4*)src)[i];
            f16x4 h; h[0]=(f16)v.x; h[1]=(f16)v.y; h[2]=(f16)v.z; h[3]=(f16)v.w;
            ((f16x4*)wh)[(size_t)(y-1)*nW4 + i] = h;
        }
    }
}

// ============================================================
// Fused QKV GEMM (m97 structure), grid (37,12,3).
// z=0/1: pre-norm Q/K, f16 row-major. z=2: V, f16 panelized Vt.
// Vt panels: [head][key-group][8 kchunks][128 d][8 keys]
// ============================================================
__global__ __launch_bounds__(256) void gemm_qkv(const f16* __restrict__ A,
                                                const f16* __restrict__ Bq,
                                                const f16* __restrict__ Bk,
                                                const f16* __restrict__ Bv,
                                                const float* __restrict__ bq,
                                                const float* __restrict__ bk,
                                                const float* __restrict__ bv,
                                                f16* __restrict__ preq,
                                                f16* __restrict__ prek,
                                                f16* __restrict__ vtp) {
    int z = blockIdx.z;
    const f16* B = (z==0) ? Bq : (z==1) ? Bk : Bv;
    const float* bias = (z==0) ? bq : (z==1) ? bk : bv;

    __shared__ __align__(16) f16 Al[128 * 64];
    __shared__ __align__(16) f16 Bl[128 * 64];
    int tid = threadIdx.x;
    int lane = tid & 63, wv = tid >> 6;
    int l16 = lane & 15, quad = lane >> 4;
    int wr = (wv >> 1) * 64, wc = (wv & 1) * 64;
    int m0 = blockIdx.x * 128, n0 = blockIdx.y * 128;

    f32x4 acc[4][4] = {};

    for (int kb = 0; kb < DIMSZ; kb += 64) {
        __syncthreads();
#pragma unroll
        for (int j = 0; j < 4; j++) {
            int s = j * 256 + wv * 64 + lane;
            int r = s >> 3, cc = s & 7;
            const f16* src = A + (size_t)min(m0 + r, S_LEN - 1) * DIMSZ + kb + ((cc ^ (r & 7)) << 3);
            async16(src, (char*)Al + (j * 4096 + wv * 1024));
        }
#pragma unroll
        for (int j = 0; j < 4; j++) {
            int s = j * 256 + wv * 64 + lane;
            int r = s >> 3, cc = s & 7;
            const f16* src = B + (size_t)(n0 + r) * DIMSZ + kb + ((cc ^ (r & 7)) << 3);
            async16(src, (char*)Bl + (j * 4096 + wv * 1024));
        }
        __builtin_amdgcn_s_waitcnt(0x0f70);
        __syncthreads();

#pragma unroll
        for (int kc = 0; kc < 2; kc++) {
            f16x8 af[4], bf[4];
#pragma unroll
            for (int i = 0; i < 4; i++) {
                int ar = wr + i * 16 + l16;
                af[i] = *(const f16x8*)((const char*)Al + ar * 128 + (((kc * 4 + quad) ^ (ar & 7)) << 4));
                int br = wc + i * 16 + l16;
                bf[i] = *(const f16x8*)((const char*)Bl + br * 128 + (((kc * 4 + quad) ^ (br & 7)) << 4));
            }
#pragma unroll
            for (int mi = 0; mi < 4; mi++)
#pragma unroll
                for (int ni = 0; ni < 4; ni++)
                    acc[mi][ni] = __builtin_amdgcn_mfma_f32_16x16x32_f16(af[mi], bf[ni], acc[mi][ni], 0, 0, 0);
        }
    }

    if (z < 2) {
        f16* C = (z == 0) ? preq : prek;
#pragma unroll
        for (int mi = 0; mi < 4; mi++)
#pragma unroll
            for (int ni = 0; ni < 4; ni++) {
                int col = n0 + wc + ni * 16 + l16;
                float bv_ = bias[col];
#pragma unroll
                for (int r = 0; r < 4; r++) {
                    int row = m0 + wr + mi * 16 + quad * 4 + r;
                    if (row < S_LEN) C[(size_t)row * DIMSZ + col] = (f16)(acc[mi][ni][r] + bv_);
                }
            }
    } else {
#pragma unroll
        for (int mi = 0; mi < 4; mi++)
#pragma unroll
            for (int ni = 0; ni < 4; ni++) {
                int col  = n0 + wc + ni * 16 + l16;
                int vhead = col >> 7, d = col & 127;
                int base = m0 + wr + mi * 16 + quad * 4;   // 4 consecutive keys
                if (base < S_LEN) {
                    float bv_ = bias[col];
                    f16x4 h;
#pragma unroll
                    for (int r = 0; r < 4; r++) h[r] = (f16)(acc[mi][ni][r] + bv_);
                    size_t off = (size_t)vhead * PANH + (size_t)(base >> 6) * 8192
                               + ((base >> 3) & 7) * 1024 + d * 8 + (base & 7);
                    *(f16x4*)(vtp + off) = h;
                }
            }
    }
}

// ============================================================
// RMSNorm + RoPE -> panelized Q/K: [head][q-group][16 dchunks][64 q][8 d]
// grid (S_LEN, 2): y=0 Q, y=1 K
// ============================================================
__global__ __launch_bounds__(256) void norm_rope(const f16* __restrict__ preq,
                                                 const f16* __restrict__ prek,
                                                 const float* __restrict__ gq,
                                                 const float* __restrict__ gk,
                                                 const float* __restrict__ freqs,
                                                 f16* __restrict__ Qp,
                                                 f16* __restrict__ Kp) {
    int s = blockIdx.x, which = blockIdx.y;
    int t = threadIdx.x;
    const f16* pre = which ? prek : preq;
    const float* g = which ? gk : gq;
    f16* dst = which ? Kp : Qp;
    const f16* row = pre + (size_t)s * DIMSZ + t * 6;

    float v[6];
    float ss = 0.f;
#pragma unroll
    for (int i = 0; i < 3; i++) {
        f16x2 hp = *(const f16x2*)(row + 2 * i);
        v[2*i] = (float)hp[0]; v[2*i+1] = (float)hp[1];
        ss += v[2*i]*v[2*i] + v[2*i+1]*v[2*i+1];
    }
#pragma unroll
    for (int off = 32; off; off >>= 1) ss += __shfl_xor(ss, off);
    __shared__ float red[4];
    if ((t & 63) == 0) red[t >> 6] = ss;
    __syncthreads();
    float tot = red[0] + red[1] + red[2] + red[3];
    float rms = rsqrtf(tot * (1.0f / DIMSZ) + 1e-6f);

    int tpos = s / FRAME;
    int rem  = s % FRAME;
    int ypos = rem / 52;
    int xpos = s % 52;

#pragma unroll
    for (int u = 0; u < 3; u++) {
        int c = t * 6 + u * 2;
        int head = c >> 7;
        int d = c & 127;
        int j = d >> 1;
        int idx = (j < 22) ? tpos : ((j < 43) ? ypos : xpos);
        float ang = freqs[idx * 64 + j];
        float sn, cs;
        __sincosf(ang, &sn, &cs);
        float vr = v[u * 2]     * rms * g[c];
        float vi = v[u * 2 + 1] * rms * g[c + 1];
        f16* o = dst + (size_t)head * PANH + (size_t)(s >> 6) * 8192
               + (d >> 3) * 512 + (s & 63) * 8 + (d & 7);
        o[0] = (f16)(vr * cs - vi * sn);
        o[1] = (f16)(vr * sn + vi * cs);
    }
}

// ============================================================
// Attention partials. Block = 2 waves x 64 q (128 q-tile), head, chunk.
// Fine chunking: 2/4/6 chunks per tile by frame count -> grid (150, 12).
// 32x32x16 MFMA, S^T = K Q^T, O^T = V^T P^T.
// R7: back to R0's SINGLE 32KB K+V buffer + per-group vmcnt(0) drain
// (2 barriers/group), but at 5 blocks/CU (32KB LDS, 2.5 waves/SIMD).
// Rationale from R0-R6: the 2-wave block's per-group [MFMA 256cy |
// softmax ~450cy | drain ~600cy] phases can only overlap across
// INDEPENDENT blocks (no shared barriers). dbuf (R1) hid the drain but
// capped occupancy at 1 wave/SIMD (MfmaUtil 22%); every added barrier
// (R3/R6) lockstepped; un-staging V (R5) thrashed L2. Single-buffer
// drain at 2.5 waves/SIMD lets the CU run another block's compute
// through each drain. exp2-folded Q scale kept (saves 64 v_mul/group);
// setprio kept (independent waves per SIMD = m191's condition).
// ============================================================
__global__ __launch_bounds__(128, 2) void attn_part(const f16* __restrict__ Qp,
                                                    const f16* __restrict__ Kp,
                                                    const f16* __restrict__ Vp,
                                                    f16* __restrict__ Opart,
                                                    float* __restrict__ lpart) {
    int bx = blockIdx.x, head = blockIdx.y;
    int t, c, NC2;
    if (bx < 24)      { t = bx >> 1;             c = bx & 1;       NC2 = 2; }
    else if (bx < 72) { t = 12 + ((bx - 24) >> 2); c = (bx - 24) & 3; NC2 = 4; }
    else              { t = 24 + (bx - 72) / 6;  c = (bx - 72) % 6; NC2 = 6; }

    int qlast = min(t * 128 + 127, S_LEN - 1);
    int nfrm  = qlast / FRAME + 1;
    int kvend = nfrm * FRAME; if (kvend > S_LEN) kvend = S_LEN;
    int nG    = (kvend + 63) >> 6;
    int g0 = (c * nG) / NC2, g1 = ((c + 1) * nG) / NC2;
    int limB = ((t * 128) / FRAME + 1) * FRAME;

    int tid = threadIdx.x, lane = tid & 63, wv = tid >> 6;
    int l31 = lane & 31, lh = lane >> 5;
    int qw = t * 128 + wv * 64;

    __shared__ __align__(16) char smem[32768];   // K @0 (16KB) + V @16384 (16KB)
    const char* smc = smem;

    // Q B-frags from panelized global (coalesced), pre-scaled by
    // (1/sqrt(128)) * log2(e) so softmax uses exp2 directly
    const f16* Qg = Qp + ((size_t)head * NGRP + (qw >> 6)) * 8192;
    f16x8 bqf[2][8];
#pragma unroll
    for (int nt = 0; nt < 2; nt++)
#pragma unroll
        for (int ks = 0; ks < 8; ks++) {
            f16x8 vq = *(const f16x8*)(Qg + (2 * ks + lh) * 512 + (l31 + 32 * nt) * 8);
            bqf[nt][ks] = vq * (f16)0.12752044581f;   // 0.0883883 * 1.4426950
        }

    int lim[2];
#pragma unroll
    for (int nt = 0; nt < 2; nt++) {
        int q = qw + l31 + 32 * nt;
        lim[nt] = (q / FRAME + 1) * FRAME;
    }

    f32x16 oacc[4][2] = {};
    float lp[2] = {0.f, 0.f};

    int koff = lh * 1024 + l31 * 16;
    int voff = lh * 2048 + l31 * 16;

    const f16* Kh = Kp + (size_t)head * NGRP * 8192;
    const f16* Vh = Vp + (size_t)head * NGRP * 8192;

    for (int g = g0; g < g1; g++) {
        int kb = g * 64;
        // ---- stage K(g)+V(g); prior end-barrier protects previous reads ----
#pragma unroll
        for (int i = 0; i < 8; i++) {
            int s = i * 2 + wv;
            async16(Kh + (size_t)g * 8192 + s * 512 + lane * 8,
                    (char*)smem + s * 1024 + lane * 16);
        }
#pragma unroll
        for (int i = 0; i < 8; i++) {
            int s = i * 2 + wv;
            async16(Vh + (size_t)g * 8192 + s * 512 + lane * 8,
                    (char*)smem + 16384 + s * 1024 + lane * 16);
        }
        __builtin_amdgcn_s_waitcnt(0x0f70);   // vmcnt(0)
        __builtin_amdgcn_s_barrier();         // staged data valid for both waves

        bool domask = (kb + 64 > limB);

#pragma unroll
        for (int kt = 0; kt < 2; kt++) {
            // ---- S^T = K Q^T ----
            f32x16 sc0 = {}, sc1 = {};
            __builtin_amdgcn_s_setprio(1);
#pragma unroll
            for (int h = 0; h < 2; h++) {
                f16x8 ka[4];
#pragma unroll
                for (int i = 0; i < 4; i++)
                    ka[i] = *(const f16x8*)(smc + koff + (h * 4 + i) * 2048 + kt * 512);
#pragma unroll
                for (int i = 0; i < 4; i++) {
                    sc0 = __builtin_amdgcn_mfma_f32_32x32x16_f16(ka[i], bqf[0][h*4+i], sc0, 0, 0, 0);
                    sc1 = __builtin_amdgcn_mfma_f32_32x32x16_f16(ka[i], bqf[1][h*4+i], sc1, 0, 0, 0);
                }
            }
            __builtin_amdgcn_s_setprio(0);

            // ---- mask + exp2 + pack ----
            int w[2][8];
            int keyb = kb + kt * 32 + 4 * lh;
#pragma unroll
            for (int nt = 0; nt < 2; nt++) {
#pragma unroll
                for (int p = 0; p < 8; p++) {
                    const int r0 = 2 * p;
                    float s0 = (nt == 0) ? sc0[r0]     : sc1[r0];
                    float s1 = (nt == 0) ? sc0[r0 + 1] : sc1[r0 + 1];
                    if (domask) {
                        int k0 = keyb + (r0 & 3) + 8 * (r0 >> 2);
                        if (k0     >= lim[nt]) s0 = -1e30f;
                        if (k0 + 1 >= lim[nt]) s1 = -1e30f;
                    }
                    float p0 = fexp2(s0), p1 = fexp2(s1);
                    lp[nt] += p0 + p1;
                    PkCast pk; pk.v = __builtin_amdgcn_cvt_pkrtz(p0, p1);
                    w[nt][p] = pk.i;
                }
            }

            // ---- C-layout -> P^T B-frags (cross-half dword exchange) ----
            f16x8 pb[2][2];
#pragma unroll
            for (int nt = 0; nt < 2; nt++)
#pragma unroll
                for (int ks = 0; ks < 2; ks++) {
                    FragCast fc;
#if __has_builtin(__builtin_amdgcn_permlane32_swap)
                    v2i r02 = __builtin_amdgcn_permlane32_swap(w[nt][4*ks+0], w[nt][4*ks+2], false, false);
                    v2i r13 = __builtin_amdgcn_permlane32_swap(w[nt][4*ks+1], w[nt][4*ks+3], false, false);
                    fc.w[0] = r02.x; fc.w[1] = r13.x; fc.w[2] = r02.y; fc.w[3] = r13.y;
#else
                    int w0 = w[nt][4*ks], w1 = w[nt][4*ks+1], w2 = w[nt][4*ks+2], w3 = w[nt][4*ks+3];
                    fc.w[0] = lh ? __shfl_xor(w2, 32) : w0;
                    fc.w[1] = lh ? __shfl_xor(w3, 32) : w1;
                    fc.w[2] = lh ? w2 : __shfl_xor(w0, 32);
                    fc.w[3] = lh ? w3 : __shfl_xor(w1, 32);
#endif
                    pb[nt][ks] = fc.v;
                }

            // ---- O^T += V^T P^T (V frags shared across both n-tiles) ----
            __builtin_amdgcn_s_setprio(1);
#pragma unroll
            for (int mt = 0; mt < 4; mt++)
#pragma unroll
                for (int ks = 0; ks < 2; ks++) {
                    f16x8 va = *(const f16x8*)(smc + 16384 + voff + kt * 8192 + ks * 4096 + mt * 512);
                    oacc[mt][0] = __builtin_amdgcn_mfma_f32_32x32x16_f16(va, pb[0][ks], oacc[mt][0], 0, 0, 0);
                    oacc[mt][1] = __builtin_amdgcn_mfma_f32_32x32x16_f16(va, pb[1][ks], oacc[mt][1], 0, 0, 0);
                }
            __builtin_amdgcn_s_setprio(0);
        }

        // both waves done reading before next iter's stage overwrites
        __builtin_amdgcn_s_barrier();
    }

    // ---- l across lane-halves ----
    float lt[2], linv[2];
#pragma unroll
    for (int nt = 0; nt < 2; nt++) {
        float l = lp[nt] + __shfl_xor(lp[nt], 32);
        lt[nt] = l;
        linv[nt] = (l > 0.f) ? 1.f / l : 0.f;
    }

    // ---- epilogue through per-wave LDS (swizzled) -> coalesced global ----
    __syncthreads();
    char* ob = (char*)smem + wv * 16384;
#pragma unroll
    for (int mt = 0; mt < 4; mt++)
#pragma unroll
        for (int nt = 0; nt < 2; nt++) {
            int qloc = l31 + 32 * nt;
#pragma unroll
            for (int g4 = 0; g4 < 4; g4++) {
                f16x4 hv;
#pragma unroll
                for (int r = 0; r < 4; r++) hv[r] = (f16)(oacc[mt][nt][g4 * 4 + r] * linv[nt]);
                int c16 = g4 + 4 * mt;
                *(f16x4*)(ob + qloc * 256 + ((c16 ^ (qloc & 7)) << 4) + lh * 8) = hv;
            }
        }
    __syncthreads();

    // slot-compact partial layout: [head][slot=bx][128 q][128 d]
    size_t obase = ((size_t)(head * NSLOT + bx) * 128 + wv * 64) * HD;
#pragma unroll
    for (int a = 0; a < 4; a++)
#pragma unroll
        for (int b = 0; b < 4; b++) {
            int qloc = a * 16 + (lane >> 2);
            int c16  = (lane & 3) + 4 * b;
            f16x8 vv = *(const f16x8*)(ob + qloc * 256 + ((c16 ^ (qloc & 7)) << 4));
            *(f16x8*)(Opart + obase + (size_t)qloc * HD + c16 * 8) = vv;
        }

    if (lane < 32) {
        size_t lbase = (size_t)(head * NSLOT + bx) * 128 + wv * 64;
        lpart[lbase + l31]      = lt[0];
        lpart[lbase + l31 + 32] = lt[1];
    }
}

// ============================================================
// Combine chunk partials -> AO f16 [S][DIM]
// ============================================================
__global__ __launch_bounds__(256) void combine(const f16* __restrict__ Opart,
                                               const float* __restrict__ lpart,
                                               f16* __restrict__ AO) {
    int gid = blockIdx.x * 256 + threadIdx.x;
    if (gid >= S_LEN * NH * 16) return;
    int dc = gid & 15;
    int head = (gid >> 4) % NH;
    int q = gid / (NH * 16);
    int tt = q >> 7, qloc = q & 127;
    int base, nchunk;
    if (tt < 12)      { base = 2 * tt;             nchunk = 2; }
    else if (tt < 24) { base = 24 + 4 * (tt - 12); nchunk = 4; }
    else              { base = 72 + 6 * (tt - 24); nchunk = 6; }

    float sum[8] = {};
    float ls = 0.f;
    for (int c = 0; c < nchunk; c++) {
        size_t sbase = (size_t)(head * NSLOT + base + c) * 128 + qloc;
        float l = lpart[sbase];
        if (l > 0.f) {
            f16x8 o = *(const f16x8*)(Opart + sbase * HD + dc * 8);
#pragma unroll
            for (int j = 0; j < 8; j++) sum[j] += (float)o[j] * l;
            ls += l;
        }
    }
    float invl = 1.f / ls;
    f16x8 r;
#pragma unroll
    for (int j = 0; j < 8; j++) r[j] = (f16)(sum[j] * invl);
    *(f16x8*)(AO + (size_t)q * DIMSZ + head * HD + dc * 8) = r;
}

// ============================================================
// Output projection GEMM (m97 structure), f32 out
// ============================================================
__global__ __launch_bounds__(256) void gemm_lds(const f16* __restrict__ A,
                                                const f16* __restrict__ B,
                                                const float* __restrict__ bias,
                                                float* __restrict__ C) {
    __shared__ __align__(16) f16 Al[128 * 64];
    __shared__ __align__(16) f16 Bl[128 * 64];
    int tid = threadIdx.x;
    int lane = tid & 63, wv = tid >> 6;
    int l16 = lane & 15, quad = lane >> 4;
    int wr = (wv >> 1) * 64, wc = (wv & 1) * 64;
    int m0 = blockIdx.x * 128, n0 = blockIdx.y * 128;

    f32x4 acc[4][4] = {};

    for (int kb = 0; kb < DIMSZ; kb += 64) {
        __syncthreads();
#pragma unroll
        for (int j = 0; j < 4; j++) {
            int s = j * 256 + wv * 64 + lane;
            int r = s >> 3, cc = s & 7;
            const f16* src = A + (size_t)min(m0 + r, S_LEN - 1) * DIMSZ + kb + ((cc ^ (r & 7)) << 3);
            async16(src, (char*)Al + (j * 4096 + wv * 1024));
        }
#pragma unroll
        for (int j = 0; j < 4; j++) {
            int s = j * 256 + wv * 64 + lane;
            int r = s >> 3, cc = s & 7;
            const f16* src = B + (size_t)(n0 + r) * DIMSZ + kb + ((cc ^ (r & 7)) << 3);
            async16(src, (char*)Bl + (j * 4096 + wv * 1024));
        }
        __builtin_amdgcn_s_waitcnt(0x0f70);
        __syncthreads();

#pragma unroll
        for (int kc = 0; kc < 2; kc++) {
            f16x8 af[4], bf[4];
#pragma unroll
            for (int i = 0; i < 4; i++) {
                int ar = wr + i * 16 + l16;
                af[i] = *(const f16x8*)((const char*)Al + ar * 128 + (((kc * 4 + quad) ^ (ar & 7)) << 4));
                int br = wc + i * 16 + l16;
                bf[i] = *(const f16x8*)((const char*)Bl + br * 128 + (((kc * 4 + quad) ^ (br & 7)) << 4));
            }
#pragma unroll
            for (int mi = 0; mi < 4; mi++)
#pragma unroll
                for (int ni = 0; ni < 4; ni++)
                    acc[mi][ni] = __builtin_amdgcn_mfma_f32_16x16x32_f16(af[mi], bf[ni], acc[mi][ni], 0, 0, 0);
        }
    }

#pragma unroll
    for (int mi = 0; mi < 4; mi++)
#pragma unroll
        for (int ni = 0; ni < 4; ni++) {
            int col = n0 + wc + ni * 16 + l16;
            float bv = bias[col];
#pragma unroll
            for (int r = 0; r < 4; r++) {
                int row = m0 + wr + mi * 16 + quad * 4 + r;
                if (row < S_LEN) C[(size_t)row * DIMSZ + col] = acc[mi][ni][r] + bv;
            }
        }
}

// ============================================================
// host launch
// ============================================================
extern "C" void kernel_launch(void* const* d_in, const int* in_sizes, int n_in,
                              void* d_out, int out_size, void* d_ws, size_t ws_size,
                              hipStream_t stream) {
    const float* x     = (const float*)d_in[0];
    const float* freqs = (const float*)d_in[3];
    const float* Wq = (const float*)d_in[4];
    const float* bq = (const float*)d_in[5];
    const float* Wk = (const float*)d_in[6];
    const float* bk = (const float*)d_in[7];
    const float* Wv = (const float*)d_in[8];
    const float* bv = (const float*)d_in[9];
    const float* Wo = (const float*)d_in[10];
    const float* bo = (const float*)d_in[11];
    const float* gq = (const float*)d_in[12];
    const float* gk = (const float*)d_in[13];
    float* out = (float*)d_out;

    char* ws = (char*)d_ws;
    const size_t SZ_XH  = (size_t)S_LEN * DIMSZ * 2;     // 14,376,960
    const size_t SZ_W   = (size_t)DIMSZ * DIMSZ * 2;     //  4,718,592
    const size_t SZ_PAN = (size_t)NH * PANH * 2;         // 14,548,992
    const size_t SZ_OP  = (size_t)NH * NSLOT * 128 * HD * 2;  // 58,982,400

    size_t off = 0;
    f16* xh   = (f16*)(ws + off); off += SZ_XH;
    f16* wqh  = (f16*)(ws + off); off += 4 * SZ_W;       // wq,wk,wv,wo contiguous
    f16* wkh  = wqh + (size_t)DIMSZ * DIMSZ;
    f16* wvh  = wkh + (size_t)DIMSZ * DIMSZ;
    f16* woh  = wvh + (size_t)DIMSZ * DIMSZ;
    f16* Qpan = (f16*)(ws + off); off += SZ_PAN;
    f16* Kpan = (f16*)(ws + off); off += SZ_PAN;
    f16* Vpan = (f16*)(ws + off); off += SZ_PAN;
    // AO aliases Qpan: Qpan is dead after attn_part; combine writes AO
    // strictly after (stream-ordered). Keeps total ws at ~137 MB.
    f16* AO   = Qpan;
    // union: {preq, prek} (f16) before attention | {Opart, lpart} after
    f16*   preq  = (f16*)(ws + off);
    f16*   prek  = preq + (size_t)S_LEN * DIMSZ;
    f16*   Opart = (f16*)(ws + off);
    float* lpart = (float*)(ws + off + SZ_OP);

    cast_all<<<dim3(7020, 5), 256, 0, stream>>>(x, Wq, Wk, Wv, Wo, xh, wqh);

    gemm_qkv<<<dim3(37, 12, 3), 256, 0, stream>>>(xh, wqh, wkh, wvh, bq, bk, bv,
                                                  preq, prek, Vpan);

    norm_rope<<<dim3(S_LEN, 2), 256, 0, stream>>>(preq, prek, gq, gk, freqs, Qpan, Kpan);

    attn_part<<<dim3(NSLOT, 12), 128, 0, stream>>>(Qpan, Kpan, Vpan, Opart, lpart);
    combine<<<(S_LEN * NH * 16 + 255) / 256, 256, 0, stream>>>(Opart, lpart, AO);

    gemm_lds<<<dim3(37, 12), 256, 0, stream>>>(AO, woh, bo, out);
}

// Round 8
// 488.654 us; speedup vs baseline: 1.4919x; 1.0107x over previous
//
#include <hip/hip_runtime.h>
#include <hip/hip_bf16.h>
#include <math.h>
#include <stdint.h>

// ---- problem constants ----
#define S_LEN 4680
#define DIMSZ 1536
#define NH    12
#define HD    128
#define FRAME 1560
#define NGRP  74        // padded 64-key/-q groups (74*64 = 4736)
#define PANH  (NGRP * 8192)   // f16 elems per head in a panelized tensor
#define NSLOT 150       // (q-tile, chunk) slots per head: 12*2 + 12*4 + 13*6

typedef _Float16 f16;
typedef _Float16 f16x8 __attribute__((ext_vector_type(8)));
typedef _Float16 f16x4 __attribute__((ext_vector_type(4)));
typedef _Float16 f16x2 __attribute__((ext_vector_type(2)));
typedef __fp16   fp16x2 __attribute__((ext_vector_type(2)));
typedef float    f32x4  __attribute__((ext_vector_type(4)));
typedef float    f32x16 __attribute__((ext_vector_type(16)));
typedef int      v2i    __attribute__((ext_vector_type(2)));

__device__ __forceinline__ void async16(const void* g, void* l) {
    __builtin_amdgcn_global_load_lds((const __attribute__((address_space(1))) void*)g,
                                     (__attribute__((address_space(3))) void*)l, 16, 0, 0);
}

__device__ __forceinline__ float fexp2(float x) {
#if __has_builtin(__builtin_amdgcn_exp2f)
    return __builtin_amdgcn_exp2f(x);
#else
    return exp2f(x);
#endif
}

union PkCast { fp16x2 v; int i; };
union FragCast { int w[4]; f16x8 v; };

// ============================================================
// all f32->f16 casts in one dispatch: y=0 x, y=1..4 weights
// ============================================================
__global__ __launch_bounds__(256) void cast_all(const float* __restrict__ x,
                                                const float* __restrict__ wq,
                                                const float* __restrict__ wk,
                                                const float* __restrict__ wv,
                                                const float* __restrict__ wo,
                                                f16* __restrict__ xh,
                                                f16* __restrict__ wh) {
    int y = blockIdx.y;
    int i = blockIdx.x * 256 + threadIdx.x;
    if (y == 0) {
        if (i < (S_LEN * DIMSZ) / 4) {
            float4 v = ((const float4*)x)[i];
            f16x4 h; h[0]=(f16)v.x; h[1]=(f16)v.y; h[2]=(f16)v.z; h[3]=(f16)v.w;
            ((f16x4*)xh)[i] = h;
        }
    } else {
        const int nW4 = (DIMSZ * DIMSZ) / 4;
        if (i < nW4) {
            const float* src = (y==1)?wq:(y==2)?wk:(y==3)?wv:wo;
            float4 v = ((const float4*)src)[i];
            f16x4 h; h[0]=(f16)v.x; h[1]=(f16)v.y; h[2]=(f16)v.z; h[3]=(f16)v.w;
            ((f16x4*)wh)[(size_t)(y-1)*nW4 + i] = h;
        }
    }
}

// ============================================================
// Fused QKV GEMM (m97 structure), grid (37,12,3).
// z=0/1: pre-norm Q/K, f16 row-major. z=2: V, f16 panelized Vt.
// Vt panels: [head][key-group][8 kchunks][128 d][8 keys]
// ============================================================
__global__ __launch_bounds__(256) void gemm_qkv(const f16* __restrict__ A,
                                                const f16* __restrict__ Bq,
                                                const f16* __restrict__ Bk,
                                                const f16* __restrict__ Bv,
                                                const float* __restrict__ bq,
                                                const float* __restrict__ bk,
                                                const float* __restrict__ bv,
                                                f16* __restrict__ preq,
                                                f16* __restrict__ prek,
                                                f16* __restrict__ vtp) {
    int z = blockIdx.z;
    const f16* B = (z==0) ? Bq : (z==1) ? Bk : Bv;
    const float* bias = (z==0) ? bq : (z==1) ? bk : bv;

    __shared__ __align__(16) f16 Al[128 * 64];
    __shared__ __align__(16) f16 Bl[128 * 64];
    int tid = threadIdx.x;
    int lane = tid & 63, wv = tid >> 6;
    int l16 = lane & 15, quad = lane >> 4;
    int wr = (wv >> 1) * 64, wc = (wv & 1) * 64;
    int m0 = blockIdx.x * 128, n0 = blockIdx.y * 128;

    f32x4 acc[4][4] = {};

    for (int kb = 0; kb < DIMSZ; kb += 64) {
        __syncthreads();
#pragma unroll
        for (int j = 0; j < 4; j++) {
            int s = j * 256 + wv * 64 + lane;
            int r = s >> 3, cc = s & 7;
            const f16* src = A + (size_t)min(m0 + r, S_LEN - 1) * DIMSZ + kb + ((cc ^ (r & 7)) << 3);
            async16(src, (char*)Al + (j * 4096 + wv * 1024));
        }
#pragma unroll
        for (int j = 0; j < 4; j++) {
            int s = j * 256 + wv * 64 + lane;
            int r = s >> 3, cc = s & 7;
            const f16* src = B + (size_t)(n0 + r) * DIMSZ + kb + ((cc ^ (r & 7)) << 3);
            async16(src, (char*)Bl + (j * 4096 + wv * 1024));
        }
        __builtin_amdgcn_s_waitcnt(0x0f70);
        __syncthreads();

#pragma unroll
        for (int kc = 0; kc < 2; kc++) {
            f16x8 af[4], bf[4];
#pragma unroll
            for (int i = 0; i < 4; i++) {
                int ar = wr + i * 16 + l16;
                af[i] = *(const f16x8*)((const char*)Al + ar * 128 + (((kc * 4 + quad) ^ (ar & 7)) << 4));
                int br = wc + i * 16 + l16;
                bf[i] = *(const f16x8*)((const char*)Bl + br * 128 + (((kc * 4 + quad) ^ (br & 7)) << 4));
            }
#pragma unroll
            for (int mi = 0; mi < 4; mi++)
#pragma unroll
                for (int ni = 0; ni < 4; ni++)
                    acc[mi][ni] = __builtin_amdgcn_mfma_f32_16x16x32_f16(af[mi], bf[ni], acc[mi][ni], 0, 0, 0);
        }
    }

    if (z < 2) {
        f16* C = (z == 0) ? preq : prek;
#pragma unroll
        for (int mi = 0; mi < 4; mi++)
#pragma unroll
            for (int ni = 0; ni < 4; ni++) {
                int col = n0 + wc + ni * 16 + l16;
                float bv_ = bias[col];
#pragma unroll
                for (int r = 0; r < 4; r++) {
                    int row = m0 + wr + mi * 16 + quad * 4 + r;
                    if (row < S_LEN) C[(size_t)row * DIMSZ + col] = (f16)(acc[mi][ni][r] + bv_);
                }
            }
    } else {
#pragma unroll
        for (int mi = 0; mi < 4; mi++)
#pragma unroll
            for (int ni = 0; ni < 4; ni++) {
                int col  = n0 + wc + ni * 16 + l16;
                int vhead = col >> 7, d = col & 127;
                int base = m0 + wr + mi * 16 + quad * 4;   // 4 consecutive keys
                if (base < S_LEN) {
                    float bv_ = bias[col];
                    f16x4 h;
#pragma unroll
                    for (int r = 0; r < 4; r++) h[r] = (f16)(acc[mi][ni][r] + bv_);
                    size_t off = (size_t)vhead * PANH + (size_t)(base >> 6) * 8192
                               + ((base >> 3) & 7) * 1024 + d * 8 + (base & 7);
                    *(f16x4*)(vtp + off) = h;
                }
            }
    }
}

// ============================================================
// RMSNorm + RoPE -> panelized Q/K: [head][q-group][16 dchunks][64 q][8 d]
// grid (S_LEN, 2): y=0 Q, y=1 K
// ============================================================
__global__ __launch_bounds__(256) void norm_rope(const f16* __restrict__ preq,
                                                 const f16* __restrict__ prek,
                                                 const float* __restrict__ gq,
                                                 const float* __restrict__ gk,
                                                 const float* __restrict__ freqs,
                                                 f16* __restrict__ Qp,
                                                 f16* __restrict__ Kp) {
    int s = blockIdx.x, which = blockIdx.y;
    int t = threadIdx.x;
    const f16* pre = which ? prek : preq;
    const float* g = which ? gk : gq;
    f16* dst = which ? Kp : Qp;
    const f16* row = pre + (size_t)s * DIMSZ + t * 6;

    float v[6];
    float ss = 0.f;
#pragma unroll
    for (int i = 0; i < 3; i++) {
        f16x2 hp = *(const f16x2*)(row + 2 * i);
        v[2*i] = (float)hp[0]; v[2*i+1] = (float)hp[1];
        ss += v[2*i]*v[2*i] + v[2*i+1]*v[2*i+1];
    }
#pragma unroll
    for (int off = 32; off; off >>= 1) ss += __shfl_xor(ss, off);
    __shared__ float red[4];
    if ((t & 63) == 0) red[t >> 6] = ss;
    __syncthreads();
    float tot = red[0] + red[1] + red[2] + red[3];
    float rms = rsqrtf(tot * (1.0f / DIMSZ) + 1e-6f);

    int tpos = s / FRAME;
    int rem  = s % FRAME;
    int ypos = rem / 52;
    int xpos = s % 52;

#pragma unroll
    for (int u = 0; u < 3; u++) {
        int c = t * 6 + u * 2;
        int head = c >> 7;
        int d = c & 127;
        int j = d >> 1;
        int idx = (j < 22) ? tpos : ((j < 43) ? ypos : xpos);
        float ang = freqs[idx * 64 + j];
        float sn, cs;
        __sincosf(ang, &sn, &cs);
        float vr = v[u * 2]     * rms * g[c];
        float vi = v[u * 2 + 1] * rms * g[c + 1];
        f16* o = dst + (size_t)head * PANH + (size_t)(s >> 6) * 8192
               + (d >> 3) * 512 + (s & 63) * 8 + (d & 7);
        o[0] = (f16)(vr * cs - vi * sn);
        o[1] = (f16)(vr * sn + vi * cs);
    }
}

// ============================================================
// Attention partials. Block = 2 waves x 64 q (128 q-tile), head, chunk.
// Fine chunking: 2/4/6 chunks per tile by frame count -> grid (150, 12).
// 32x32x16 MFMA, S^T = K Q^T, O^T = V^T P^T.
// R8: R1's verified schedule (double-buffer + prefetch + counted vmcnt,
// 2 barriers/tile, no mid-loop gates) at HALF the tile: 32-key subgroups.
// LDS = K dbuf 2x8KB (@0/@8192) + V dbuf 2x8KB (@16384/@24576) = 32KB
// -> 5 blocks/CU (2.5 waves/SIMD) vs R1's 2 (1 wave/SIMD). This fills
// the untested {counted-dbuf x high-occupancy} quadrant: R0/R7 showed
// drain can't be hidden by TLP; R1 showed the dbuf hides the drain but
// has no TLP. Panel layouts split cleanly at 32 keys (K: 512B halves
// per dchunk; V: kchunks 0-3/4-7 contiguous 8KB). Per-key bytes, MFMA,
// exp work identical to R1; loop/barrier count doubles but overlaps
// across 5 independent blocks. exp2-folded Q scale + setprio kept.
// ============================================================
__global__ __launch_bounds__(128, 2) void attn_part(const f16* __restrict__ Qp,
                                                    const f16* __restrict__ Kp,
                                                    const f16* __restrict__ Vp,
                                                    f16* __restrict__ Opart,
                                                    float* __restrict__ lpart) {
    int bx = blockIdx.x, head = blockIdx.y;
    int t, c, NC2;
    if (bx < 24)      { t = bx >> 1;             c = bx & 1;       NC2 = 2; }
    else if (bx < 72) { t = 12 + ((bx - 24) >> 2); c = (bx - 24) & 3; NC2 = 4; }
    else              { t = 24 + (bx - 72) / 6;  c = (bx - 72) % 6; NC2 = 6; }

    int qlast = min(t * 128 + 127, S_LEN - 1);
    int nfrm  = qlast / FRAME + 1;
    int kvend = nfrm * FRAME; if (kvend > S_LEN) kvend = S_LEN;
    int nG    = (kvend + 63) >> 6;
    int g0 = (c * nG) / NC2, g1 = ((c + 1) * nG) / NC2;
    int limB = ((t * 128) / FRAME + 1) * FRAME;

    int tid = threadIdx.x, lane = tid & 63, wv = tid >> 6;
    int l31 = lane & 31, lh = lane >> 5;
    int qw = t * 128 + wv * 64;

    // K0@0, K1@8192, V0@16384, V1@24576
    __shared__ __align__(16) char smem[32768];

    // Q B-frags from panelized global (coalesced), pre-scaled by
    // (1/sqrt(128)) * log2(e) so softmax uses exp2 directly
    const f16* Qg = Qp + ((size_t)head * NGRP + (qw >> 6)) * 8192;
    f16x8 bqf[2][8];
#pragma unroll
    for (int nt = 0; nt < 2; nt++)
#pragma unroll
        for (int ks = 0; ks < 8; ks++) {
            f16x8 vq = *(const f16x8*)(Qg + (2 * ks + lh) * 512 + (l31 + 32 * nt) * 8);
            bqf[nt][ks] = vq * (f16)0.12752044581f;   // 0.0883883 * 1.4426950
        }

    int lim[2];
#pragma unroll
    for (int nt = 0; nt < 2; nt++) {
        int q = qw + l31 + 32 * nt;
        lim[nt] = (q / FRAME + 1) * FRAME;
    }

    f32x16 oacc[4][2] = {};
    float lp[2] = {0.f, 0.f};

    int koff = lh * 512 + l31 * 16;
    int voff = lh * 2048 + l31 * 16;

    const f16* Kh = Kp + (size_t)head * NGRP * 8192;
    const f16* Vh = Vp + (size_t)head * NGRP * 8192;

    int sg0 = 2 * g0, sg1 = 2 * g1;

    // stage 32-key subgroup sg into buffer b: 4 K + 4 V async16 per wave.
    // K image [8 dchunk-pairs][2 sub][32 s][8 d]; V image = linear byte
    // copy of the subgroup's 4 contiguous kchunks.
#define STAGE_SG(sg_, b_)                                                        \
    {                                                                            \
        int _sg = (sg_);                                                         \
        size_t _kb = (size_t)(_sg >> 1) * 8192 + (_sg & 1) * 256;                \
        const f16* _vg = Vh + (size_t)(_sg >> 1) * 8192 + (_sg & 1) * 4096;      \
        _Pragma("unroll")                                                        \
        for (int j = 0; j < 4; j++) {                                            \
            int sl = j * 2 + wv;                                                 \
            async16(Kh + _kb + (size_t)(sl * 2 + lh) * 512 + l31 * 8,            \
                    (char*)smem + (b_) * 8192 + sl * 1024 + lane * 16);          \
        }                                                                        \
        _Pragma("unroll")                                                        \
        for (int j = 0; j < 4; j++) {                                            \
            int sl = j * 2 + wv;                                                 \
            async16(_vg + sl * 512 + lane * 8,                                   \
                    (char*)smem + 16384 + (b_) * 8192 + sl * 1024 + lane * 16);  \
        }                                                                        \
    }

    // ---- prologue: stage subgroup sg0 into buffer 0 ----
    STAGE_SG(sg0, 0);

    int cur = 0;
    for (int sg = sg0; sg < sg1; sg++) {
        int kb = sg * 32;

        // ---- prefetch next subgroup into the other buffer, counted wait ----
        if (sg + 1 < sg1) {
            STAGE_SG(sg + 1, cur ^ 1);
            // 16 outstanding/wave: oldest 8 = this subgroup, newest 8 = next.
            asm volatile("s_waitcnt vmcnt(8)" ::: "memory");
        } else {
            asm volatile("s_waitcnt vmcnt(0)" ::: "memory");
        }
        __builtin_amdgcn_s_barrier();

        const char* smcK = (const char*)smem + cur * 8192;
        const char* smcV = (const char*)smem + 16384 + cur * 8192;
        bool domask = (kb + 32 > limB);

        // ---- S^T = K Q^T (8 k-slices of 16) ----
        f32x16 sc0 = {}, sc1 = {};
        __builtin_amdgcn_s_setprio(1);
#pragma unroll
        for (int h = 0; h < 2; h++) {
            f16x8 ka[4];
#pragma unroll
            for (int i = 0; i < 4; i++)
                ka[i] = *(const f16x8*)(smcK + koff + (h * 4 + i) * 1024);
#pragma unroll
            for (int i = 0; i < 4; i++) {
                sc0 = __builtin_amdgcn_mfma_f32_32x32x16_f16(ka[i], bqf[0][h*4+i], sc0, 0, 0, 0);
                sc1 = __builtin_amdgcn_mfma_f32_32x32x16_f16(ka[i], bqf[1][h*4+i], sc1, 0, 0, 0);
            }
        }
        __builtin_amdgcn_s_setprio(0);

        // ---- mask + exp2 + pack ----
        int w[2][8];
        int keyb = kb + 4 * lh;
#pragma unroll
        for (int nt = 0; nt < 2; nt++) {
#pragma unroll
            for (int p = 0; p < 8; p++) {
                const int r0 = 2 * p;
                float s0 = (nt == 0) ? sc0[r0]     : sc1[r0];
                float s1 = (nt == 0) ? sc0[r0 + 1] : sc1[r0 + 1];
                if (domask) {
                    int k0 = keyb + (r0 & 3) + 8 * (r0 >> 2);
                    if (k0     >= lim[nt]) s0 = -1e30f;
                    if (k0 + 1 >= lim[nt]) s1 = -1e30f;
                }
                float p0 = fexp2(s0), p1 = fexp2(s1);
                lp[nt] += p0 + p1;
                PkCast pk; pk.v = __builtin_amdgcn_cvt_pkrtz(p0, p1);
                w[nt][p] = pk.i;
            }
        }

        // ---- C-layout -> P^T B-frags (cross-half dword exchange) ----
        f16x8 pb[2][2];
#pragma unroll
        for (int nt = 0; nt < 2; nt++)
#pragma unroll
            for (int ks = 0; ks < 2; ks++) {
                FragCast fc;
#if __has_builtin(__builtin_amdgcn_permlane32_swap)
                v2i r02 = __builtin_amdgcn_permlane32_swap(w[nt][4*ks+0], w[nt][4*ks+2], false, false);
                v2i r13 = __builtin_amdgcn_permlane32_swap(w[nt][4*ks+1], w[nt][4*ks+3], false, false);
                fc.w[0] = r02.x; fc.w[1] = r13.x; fc.w[2] = r02.y; fc.w[3] = r13.y;
#else
                int w0 = w[nt][4*ks], w1 = w[nt][4*ks+1], w2 = w[nt][4*ks+2], w3 = w[nt][4*ks+3];
                fc.w[0] = lh ? __shfl_xor(w2, 32) : w0;
                fc.w[1] = lh ? __shfl_xor(w3, 32) : w1;
                fc.w[2] = lh ? w2 : __shfl_xor(w0, 32);
                fc.w[3] = lh ? w3 : __shfl_xor(w1, 32);
#endif
                pb[nt][ks] = fc.v;
            }

        // ---- O^T += V^T P^T (V frags shared across both n-tiles) ----
        __builtin_amdgcn_s_setprio(1);
#pragma unroll
        for (int mt = 0; mt < 4; mt++)
#pragma unroll
            for (int ks = 0; ks < 2; ks++) {
                f16x8 va = *(const f16x8*)(smcV + ks * 4096 + voff + mt * 512);
                oacc[mt][0] = __builtin_amdgcn_mfma_f32_32x32x16_f16(va, pb[0][ks], oacc[mt][0], 0, 0, 0);
                oacc[mt][1] = __builtin_amdgcn_mfma_f32_32x32x16_f16(va, pb[1][ks], oacc[mt][1], 0, 0, 0);
            }
        __builtin_amdgcn_s_setprio(0);

        // both waves done reading buf[cur] before next iter's stage overwrites
        __builtin_amdgcn_s_barrier();
        cur ^= 1;
    }
#undef STAGE_SG

    // ---- l across lane-halves ----
    float lt[2], linv[2];
#pragma unroll
    for (int nt = 0; nt < 2; nt++) {
        float l = lp[nt] + __shfl_xor(lp[nt], 32);
        lt[nt] = l;
        linv[nt] = (l > 0.f) ? 1.f / l : 0.f;
    }

    // ---- epilogue through per-wave LDS (swizzled) -> coalesced global ----
    __syncthreads();
    char* ob = (char*)smem + wv * 16384;
#pragma unroll
    for (int mt = 0; mt < 4; mt++)
#pragma unroll
        for (int nt = 0; nt < 2; nt++) {
            int qloc = l31 + 32 * nt;
#pragma unroll
            for (int g4 = 0; g4 < 4; g4++) {
                f16x4 hv;
#pragma unroll
                for (int r = 0; r < 4; r++) hv[r] = (f16)(oacc[mt][nt][g4 * 4 + r] * linv[nt]);
                int c16 = g4 + 4 * mt;
                *(f16x4*)(ob + qloc * 256 + ((c16 ^ (qloc & 7)) << 4) + lh * 8) = hv;
            }
        }
    __syncthreads();

    // slot-compact partial layout: [head][slot=bx][128 q][128 d]
    size_t obase = ((size_t)(head * NSLOT + bx) * 128 + wv * 64) * HD;
#pragma unroll
    for (int a = 0; a < 4; a++)
#pragma unroll
        for (int b = 0; b < 4; b++) {
            int qloc = a * 16 + (lane >> 2);
            int c16  = (lane & 3) + 4 * b;
            f16x8 vv = *(const f16x8*)(ob + qloc * 256 + ((c16 ^ (qloc & 7)) << 4));
            *(f16x8*)(Opart + obase + (size_t)qloc * HD + c16 * 8) = vv;
        }

    if (lane < 32) {
        size_t lbase = (size_t)(head * NSLOT + bx) * 128 + wv * 64;
        lpart[lbase + l31]      = lt[0];
        lpart[lbase + l31 + 32] = lt[1];
    }
}

// ============================================================
// Combine chunk partials -> AO f16 [S][DIM]
// ============================================================
__global__ __launch_bounds__(256) void combine(const f16* __restrict__ Opart,
                                               const float* __restrict__ lpart,
                                               f16* __restrict__ AO) {
    int gid = blockIdx.x * 256 + threadIdx.x;
    if (gid >= S_LEN * NH * 16) return;
    int dc = gid & 15;
    int head = (gid >> 4) % NH;
    int q = gid / (NH * 16);
    int tt = q >> 7, qloc = q & 127;
    int base, nchunk;
    if (tt < 12)      { base = 2 * tt;             nchunk = 2; }
    else if (tt < 24) { base = 24 + 4 * (tt - 12); nchunk = 4; }
    else              { base = 72 + 6 * (tt - 24); nchunk = 6; }

    float sum[8] = {};
    float ls = 0.f;
    for (int c = 0; c < nchunk; c++) {
        size_t sbase = (size_t)(head * NSLOT + base + c) * 128 + qloc;
        float l = lpart[sbase];
        if (l > 0.f) {
            f16x8 o = *(const f16x8*)(Opart + sbase * HD + dc * 8);
#pragma unroll
            for (int j = 0; j < 8; j++) sum[j] += (float)o[j] * l;
            ls += l;
        }
    }
    float invl = 1.f / ls;
    f16x8 r;
#pragma unroll
    for (int j = 0; j < 8; j++) r[j] = (f16)(sum[j] * invl);
    *(f16x8*)(AO + (size_t)q * DIMSZ + head * HD + dc * 8) = r;
}

// ============================================================
// Output projection GEMM (m97 structure), f32 out
// ============================================================
__global__ __launch_bounds__(256) void gemm_lds(const f16* __restrict__ A,
                                                const f16* __restrict__ B,
                                                const float* __restrict__ bias,
                                                float* __restrict__ C) {
    __shared__ __align__(16) f16 Al[128 * 64];
    __shared__ __align__(16) f16 Bl[128 * 64];
    int tid = threadIdx.x;
    int lane = tid & 63, wv = tid >> 6;
    int l16 = lane & 15, quad = lane >> 4;
    int wr = (wv >> 1) * 64, wc = (wv & 1) * 64;
    int m0 = blockIdx.x * 128, n0 = blockIdx.y * 128;

    f32x4 acc[4][4] = {};

    for (int kb = 0; kb < DIMSZ; kb += 64) {
        __syncthreads();
#pragma unroll
        for (int j = 0; j < 4; j++) {
            int s = j * 256 + wv * 64 + lane;
            int r = s >> 3, cc = s & 7;
            const f16* src = A + (size_t)min(m0 + r, S_LEN - 1) * DIMSZ + kb + ((cc ^ (r & 7)) << 3);
            async16(src, (char*)Al + (j * 4096 + wv * 1024));
        }
#pragma unroll
        for (int j = 0; j < 4; j++) {
            int s = j * 256 + wv * 64 + lane;
            int r = s >> 3, cc = s & 7;
            const f16* src = B + (size_t)(n0 + r) * DIMSZ + kb + ((cc ^ (r & 7)) << 3);
            async16(src, (char*)Bl + (j * 4096 + wv * 1024));
        }
        __builtin_amdgcn_s_waitcnt(0x0f70);
        __syncthreads();

#pragma unroll
        for (int kc = 0; kc < 2; kc++) {
            f16x8 af[4], bf[4];
#pragma unroll
            for (int i = 0; i < 4; i++) {
                int ar = wr + i * 16 + l16;
                af[i] = *(const f16x8*)((const char*)Al + ar * 128 + (((kc * 4 + quad) ^ (ar & 7)) << 4));
                int br = wc + i * 16 + l16;
                bf[i] = *(const f16x8*)((const char*)Bl + br * 128 + (((kc * 4 + quad) ^ (br & 7)) << 4));
            }
#pragma unroll
            for (int mi = 0; mi < 4; mi++)
#pragma unroll
                for (int ni = 0; ni < 4; ni++)
                    acc[mi][ni] = __builtin_amdgcn_mfma_f32_16x16x32_f16(af[mi], bf[ni], acc[mi][ni], 0, 0, 0);
        }
    }

#pragma unroll
    for (int mi = 0; mi < 4; mi++)
#pragma unroll
        for (int ni = 0; ni < 4; ni++) {
            int col = n0 + wc + ni * 16 + l16;
            float bv = bias[col];
#pragma unroll
            for (int r = 0; r < 4; r++) {
                int row = m0 + wr + mi * 16 + quad * 4 + r;
                if (row < S_LEN) C[(size_t)row * DIMSZ + col] = acc[mi][ni][r] + bv;
            }
        }
}

// ============================================================
// host launch
// ============================================================
extern "C" void kernel_launch(void* const* d_in, const int* in_sizes, int n_in,
                              void* d_out, int out_size, void* d_ws, size_t ws_size,
                              hipStream_t stream) {
    const float* x     = (const float*)d_in[0];
    const float* freqs = (const float*)d_in[3];
    const float* Wq = (const float*)d_in[4];
    const float* bq = (const float*)d_in[5];
    const float* Wk = (const float*)d_in[6];
    const float* bk = (const float*)d_in[7];
    const float* Wv = (const float*)d_in[8];
    const float* bv = (const float*)d_in[9];
    const float* Wo = (const float*)d_in[10];
    const float* bo = (const float*)d_in[11];
    const float* gq = (const float*)d_in[12];
    const float* gk = (const float*)d_in[13];
    float* out = (float*)d_out;

    char* ws = (char*)d_ws;
    const size_t SZ_XH  = (size_t)S_LEN * DIMSZ * 2;     // 14,376,960
    const size_t SZ_W   = (size_t)DIMSZ * DIMSZ * 2;     //  4,718,592
    const size_t SZ_PAN = (size_t)NH * PANH * 2;         // 14,548,992
    const size_t SZ_OP  = (size_t)NH * NSLOT * 128 * HD * 2;  // 58,982,400

    size_t off = 0;
    f16* xh   = (f16*)(ws + off); off += SZ_XH;
    f16* wqh  = (f16*)(ws + off); off += 4 * SZ_W;       // wq,wk,wv,wo contiguous
    f16* wkh  = wqh + (size_t)DIMSZ * DIMSZ;
    f16* wvh  = wkh + (size_t)DIMSZ * DIMSZ;
    f16* woh  = wvh + (size_t)DIMSZ * DIMSZ;
    f16* Qpan = (f16*)(ws + off); off += SZ_PAN;
    f16* Kpan = (f16*)(ws + off); off += SZ_PAN;
    f16* Vpan = (f16*)(ws + off); off += SZ_PAN;
    // AO aliases Qpan: Qpan is dead after attn_part; combine writes AO
    // strictly after (stream-ordered). Keeps total ws at ~137 MB.
    f16* AO   = Qpan;
    // union: {preq, prek} (f16) before attention | {Opart, lpart} after
    f16*   preq  = (f16*)(ws + off);
    f16*   prek  = preq + (size_t)S_LEN * DIMSZ;
    f16*   Opart = (f16*)(ws + off);
    float* lpart = (float*)(ws + off + SZ_OP);

    cast_all<<<dim3(7020, 5), 256, 0, stream>>>(x, Wq, Wk, Wv, Wo, xh, wqh);

    gemm_qkv<<<dim3(37, 12, 3), 256, 0, stream>>>(xh, wqh, wkh, wvh, bq, bk, bv,
                                                  preq, prek, Vpan);

    norm_rope<<<dim3(S_LEN, 2), 256, 0, stream>>>(preq, prek, gq, gk, freqs, Qpan, Kpan);

    attn_part<<<dim3(NSLOT, 12), 128, 0, stream>>>(Qpan, Kpan, Vpan, Opart, lpart);
    combine<<<(S_LEN * NH * 16 + 255) / 256, 256, 0, stream>>>(Opart, lpart, AO);

    gemm_lds<<<dim3(37, 12), 256, 0, stream>>>(AO, woh, bo, out);
}

// Round 9
// 470.401 us; speedup vs baseline: 1.5498x; 1.0388x over previous
//
#include <hip/hip_runtime.h>
#include <hip/hip_bf16.h>
#include <math.h>
#include <stdint.h>

// ---- problem constants ----
#define S_LEN 4680
#define DIMSZ 1536
#define NH    12
#define HD    128
#define FRAME 1560
#define NGRP  74        // padded 64-key/-q groups (74*64 = 4736)
#define PANH  (NGRP * 8192)   // f16 elems per head in a panelized tensor
#define NSLOT 150       // (q-tile, chunk) slots per head: 12*2 + 12*4 + 13*6

typedef _Float16 f16;
typedef _Float16 f16x8 __attribute__((ext_vector_type(8)));
typedef _Float16 f16x4 __attribute__((ext_vector_type(4)));
typedef _Float16 f16x2 __attribute__((ext_vector_type(2)));
typedef __fp16   fp16x2 __attribute__((ext_vector_type(2)));
typedef float    f32x4  __attribute__((ext_vector_type(4)));
typedef float    f32x16 __attribute__((ext_vector_type(16)));
typedef int      v2i    __attribute__((ext_vector_type(2)));

__device__ __forceinline__ void async16(const void* g, void* l) {
    __builtin_amdgcn_global_load_lds((const __attribute__((address_space(1))) void*)g,
                                     (__attribute__((address_space(3))) void*)l, 16, 0, 0);
}

__device__ __forceinline__ float fexp2(float x) {
#if __has_builtin(__builtin_amdgcn_exp2f)
    return __builtin_amdgcn_exp2f(x);
#else
    return exp2f(x);
#endif
}

union PkCast { fp16x2 v; int i; };
union FragCast { int w[4]; f16x8 v; };

// ============================================================
// all f32->f16 casts in one 1D dispatch: blocks [0,7020) = x,
// [7020, 16236) = the four weight matrices. Exact block counts
// (7020*256 == S*D/4, 2304*256 == D*D/4) -> no bounds checks,
// no empty blocks (old 2D grid scheduled 18.9k null blocks).
// ============================================================
__global__ __launch_bounds__(256) void cast_all(const float* __restrict__ x,
                                                const float* __restrict__ wq,
                                                const float* __restrict__ wk,
                                                const float* __restrict__ wv,
                                                const float* __restrict__ wo,
                                                f16* __restrict__ xh,
                                                f16* __restrict__ wh) {
    int b = blockIdx.x;
    int tid = threadIdx.x;
    if (b < 7020) {
        int i = b * 256 + tid;
        float4 v = ((const float4*)x)[i];
        f16x4 h; h[0]=(f16)v.x; h[1]=(f16)v.y; h[2]=(f16)v.z; h[3]=(f16)v.w;
        ((f16x4*)xh)[i] = h;
    } else {
        const int nW4 = (DIMSZ * DIMSZ) / 4;   // 589,824 = 2304*256
        int wb = b - 7020;
        int y = wb / 2304;
        int i = (wb % 2304) * 256 + tid;
        const float* src = (y==0)?wq:(y==1)?wk:(y==2)?wv:wo;
        float4 v = ((const float4*)src)[i];
        f16x4 h; h[0]=(f16)v.x; h[1]=(f16)v.y; h[2]=(f16)v.z; h[3]=(f16)v.w;
        ((f16x4*)wh)[(size_t)y*nW4 + i] = h;
    }
}

// ============================================================
// Fused QKV GEMM (m97 structure), grid (37,12,3).
// z=0/1: pre-norm Q/K, f16 row-major. z=2: V, f16 panelized Vt.
// Vt panels: [head][key-group][8 kchunks][128 d][8 keys]
// ============================================================
__global__ __launch_bounds__(256) void gemm_qkv(const f16* __restrict__ A,
                                                const f16* __restrict__ Bq,
                                                const f16* __restrict__ Bk,
                                                const f16* __restrict__ Bv,
                                                const float* __restrict__ bq,
                                                const float* __restrict__ bk,
                                                const float* __restrict__ bv,
                                                f16* __restrict__ preq,
                                                f16* __restrict__ prek,
                                                f16* __restrict__ vtp) {
    int z = blockIdx.z;
    const f16* B = (z==0) ? Bq : (z==1) ? Bk : Bv;
    const float* bias = (z==0) ? bq : (z==1) ? bk : bv;

    __shared__ __align__(16) f16 Al[128 * 64];
    __shared__ __align__(16) f16 Bl[128 * 64];
    int tid = threadIdx.x;
    int lane = tid & 63, wv = tid >> 6;
    int l16 = lane & 15, quad = lane >> 4;
    int wr = (wv >> 1) * 64, wc = (wv & 1) * 64;
    int m0 = blockIdx.x * 128, n0 = blockIdx.y * 128;

    f32x4 acc[4][4] = {};

    for (int kb = 0; kb < DIMSZ; kb += 64) {
        __syncthreads();
#pragma unroll
        for (int j = 0; j < 4; j++) {
            int s = j * 256 + wv * 64 + lane;
            int r = s >> 3, cc = s & 7;
            const f16* src = A + (size_t)min(m0 + r, S_LEN - 1) * DIMSZ + kb + ((cc ^ (r & 7)) << 3);
            async16(src, (char*)Al + (j * 4096 + wv * 1024));
        }
#pragma unroll
        for (int j = 0; j < 4; j++) {
            int s = j * 256 + wv * 64 + lane;
            int r = s >> 3, cc = s & 7;
            const f16* src = B + (size_t)(n0 + r) * DIMSZ + kb + ((cc ^ (r & 7)) << 3);
            async16(src, (char*)Bl + (j * 4096 + wv * 1024));
        }
        __builtin_amdgcn_s_waitcnt(0x0f70);
        __syncthreads();

#pragma unroll
        for (int kc = 0; kc < 2; kc++) {
            f16x8 af[4], bf[4];
#pragma unroll
            for (int i = 0; i < 4; i++) {
                int ar = wr + i * 16 + l16;
                af[i] = *(const f16x8*)((const char*)Al + ar * 128 + (((kc * 4 + quad) ^ (ar & 7)) << 4));
                int br = wc + i * 16 + l16;
                bf[i] = *(const f16x8*)((const char*)Bl + br * 128 + (((kc * 4 + quad) ^ (br & 7)) << 4));
            }
#pragma unroll
            for (int mi = 0; mi < 4; mi++)
#pragma unroll
                for (int ni = 0; ni < 4; ni++)
                    acc[mi][ni] = __builtin_amdgcn_mfma_f32_16x16x32_f16(af[mi], bf[ni], acc[mi][ni], 0, 0, 0);
        }
    }

    if (z < 2) {
        f16* C = (z == 0) ? preq : prek;
#pragma unroll
        for (int mi = 0; mi < 4; mi++)
#pragma unroll
            for (int ni = 0; ni < 4; ni++) {
                int col = n0 + wc + ni * 16 + l16;
                float bv_ = bias[col];
#pragma unroll
                for (int r = 0; r < 4; r++) {
                    int row = m0 + wr + mi * 16 + quad * 4 + r;
                    if (row < S_LEN) C[(size_t)row * DIMSZ + col] = (f16)(acc[mi][ni][r] + bv_);
                }
            }
    } else {
#pragma unroll
        for (int mi = 0; mi < 4; mi++)
#pragma unroll
            for (int ni = 0; ni < 4; ni++) {
                int col  = n0 + wc + ni * 16 + l16;
                int vhead = col >> 7, d = col & 127;
                int base = m0 + wr + mi * 16 + quad * 4;   // 4 consecutive keys
                if (base < S_LEN) {
                    float bv_ = bias[col];
                    f16x4 h;
#pragma unroll
                    for (int r = 0; r < 4; r++) h[r] = (f16)(acc[mi][ni][r] + bv_);
                    size_t off = (size_t)vhead * PANH + (size_t)(base >> 6) * 8192
                               + ((base >> 3) & 7) * 1024 + d * 8 + (base & 7);
                    *(f16x4*)(vtp + off) = h;
                }
            }
    }
}

// ============================================================
// RMSNorm + RoPE -> panelized Q/K: [head][q-group][16 dchunks][64 q][8 d]
// grid (S_LEN, 2): y=0 Q, y=1 K
// ============================================================
__global__ __launch_bounds__(256) void norm_rope(const f16* __restrict__ preq,
                                                 const f16* __restrict__ prek,
                                                 const float* __restrict__ gq,
                                                 const float* __restrict__ gk,
                                                 const float* __restrict__ freqs,
                                                 f16* __restrict__ Qp,
                                                 f16* __restrict__ Kp) {
    int s = blockIdx.x, which = blockIdx.y;
    int t = threadIdx.x;
    const f16* pre = which ? prek : preq;
    const float* g = which ? gk : gq;
    f16* dst = which ? Kp : Qp;
    const f16* row = pre + (size_t)s * DIMSZ + t * 6;

    float v[6];
    float ss = 0.f;
#pragma unroll
    for (int i = 0; i < 3; i++) {
        f16x2 hp = *(const f16x2*)(row + 2 * i);
        v[2*i] = (float)hp[0]; v[2*i+1] = (float)hp[1];
        ss += v[2*i]*v[2*i] + v[2*i+1]*v[2*i+1];
    }
#pragma unroll
    for (int off = 32; off; off >>= 1) ss += __shfl_xor(ss, off);
    __shared__ float red[4];
    if ((t & 63) == 0) red[t >> 6] = ss;
    __syncthreads();
    float tot = red[0] + red[1] + red[2] + red[3];
    float rms = rsqrtf(tot * (1.0f / DIMSZ) + 1e-6f);

    int tpos = s / FRAME;
    int rem  = s % FRAME;
    int ypos = rem / 52;
    int xpos = s % 52;

#pragma unroll
    for (int u = 0; u < 3; u++) {
        int c = t * 6 + u * 2;
        int head = c >> 7;
        int d = c & 127;
        int j = d >> 1;
        int idx = (j < 22) ? tpos : ((j < 43) ? ypos : xpos);
        float ang = freqs[idx * 64 + j];
        float sn, cs;
        __sincosf(ang, &sn, &cs);
        float vr = v[u * 2]     * rms * g[c];
        float vi = v[u * 2 + 1] * rms * g[c + 1];
        f16* o = dst + (size_t)head * PANH + (size_t)(s >> 6) * 8192
               + (d >> 3) * 512 + (s & 63) * 8 + (d & 7);
        o[0] = (f16)(vr * cs - vi * sn);
        o[1] = (f16)(vr * sn + vi * cs);
    }
}

// ============================================================
// Attention partials. Block = 2 waves x 64 q (128 q-tile), head, chunk.
// Fine chunking: 2/4/6 chunks per tile by frame count -> grid (150, 12).
// 32x32x16 MFMA, S^T = K Q^T, O^T = V^T P^T.
// R9 = R1's verified-best structure (175.4us): 64KB LDS K+V double
// buffer, prefetch-then-counted-vmcnt(16), 2 barriers/group, NO setprio
// (every setprio variant measured >=183). Three safe deltas only:
// exp2-folded Q scale (validated R3-R8, removes 64 v_mul/group from
// __expf), split lp accumulation chains (reassociation, halves the
// softmax serial add chain), nothing else. R0-R8 post-mortems: all four
// {drain|counted}x{low|high occ} quadrants measured 175-200us; MfmaUtil
// pinned ~21% (=531TF/2495TF) in all -> per-wave latency chain is
// structural for the 2-wave block; this config is its optimum.
// ============================================================
__global__ __launch_bounds__(128, 2) void attn_part(const f16* __restrict__ Qp,
                                                    const f16* __restrict__ Kp,
                                                    const f16* __restrict__ Vp,
                                                    f16* __restrict__ Opart,
                                                    float* __restrict__ lpart) {
    int bx = blockIdx.x, head = blockIdx.y;
    int t, c, NC2;
    if (bx < 24)      { t = bx >> 1;             c = bx & 1;       NC2 = 2; }
    else if (bx < 72) { t = 12 + ((bx - 24) >> 2); c = (bx - 24) & 3; NC2 = 4; }
    else              { t = 24 + (bx - 72) / 6;  c = (bx - 72) % 6; NC2 = 6; }

    int qlast = min(t * 128 + 127, S_LEN - 1);
    int nfrm  = qlast / FRAME + 1;
    int kvend = nfrm * FRAME; if (kvend > S_LEN) kvend = S_LEN;
    int nG    = (kvend + 63) >> 6;
    int g0 = (c * nG) / NC2, g1 = ((c + 1) * nG) / NC2;
    int limB = ((t * 128) / FRAME + 1) * FRAME;

    int tid = threadIdx.x, lane = tid & 63, wv = tid >> 6;
    int l31 = lane & 31, lh = lane >> 5;
    int qw = t * 128 + wv * 64;

    __shared__ __align__(16) char smem[65536];

    // Q B-frags from panelized global (coalesced), pre-scaled by
    // (1/sqrt(128)) * log2(e) so softmax uses exp2 directly
    const f16* Qg = Qp + ((size_t)head * NGRP + (qw >> 6)) * 8192;
    f16x8 bqf[2][8];
#pragma unroll
    for (int nt = 0; nt < 2; nt++)
#pragma unroll
        for (int ks = 0; ks < 8; ks++) {
            f16x8 vq = *(const f16x8*)(Qg + (2 * ks + lh) * 512 + (l31 + 32 * nt) * 8);
            bqf[nt][ks] = vq * (f16)0.12752044581f;   // 0.0883883 * 1.4426950
        }

    int lim[2];
#pragma unroll
    for (int nt = 0; nt < 2; nt++) {
        int q = qw + l31 + 32 * nt;
        lim[nt] = (q / FRAME + 1) * FRAME;
    }

    f32x16 oacc[4][2] = {};
    float lpa[2] = {0.f, 0.f}, lpb[2] = {0.f, 0.f};   // split serial chains

    int koff = lh * 1024 + l31 * 16;
    int voff = lh * 2048 + l31 * 16;

    const f16* Kh = Kp + (size_t)head * NGRP * 8192;
    const f16* Vh = Vp + (size_t)head * NGRP * 8192;

    // ---- prologue: stage group g0 into buffer 0 (16 async16 per wave) ----
#pragma unroll
    for (int i = 0; i < 8; i++) {
        int s = i * 2 + wv;
        async16(Kh + (size_t)g0 * 8192 + s * 512 + lane * 8,
                (char*)smem + s * 1024 + lane * 16);
        async16(Vh + (size_t)g0 * 8192 + s * 512 + lane * 8,
                (char*)smem + 16384 + s * 1024 + lane * 16);
    }

    int cur = 0;
    for (int g = g0; g < g1; g++) {
        int kb = g * 64;

        // ---- prefetch next group into the other buffer, counted wait ----
        if (g + 1 < g1) {
            int nb = (cur ^ 1) << 15;
#pragma unroll
            for (int i = 0; i < 8; i++) {
                int s = i * 2 + wv;
                async16(Kh + (size_t)(g + 1) * 8192 + s * 512 + lane * 8,
                        (char*)smem + nb + s * 1024 + lane * 16);
                async16(Vh + (size_t)(g + 1) * 8192 + s * 512 + lane * 8,
                        (char*)smem + nb + 16384 + s * 1024 + lane * 16);
            }
            // 32 outstanding: oldest 16 = this group, newest 16 = prefetch.
            // vmcnt retires in-order -> wait this group's only.
            asm volatile("s_waitcnt vmcnt(16)" ::: "memory");
        } else {
            asm volatile("s_waitcnt vmcnt(0)" ::: "memory");
        }
        __builtin_amdgcn_s_barrier();

        const char* smc = (const char*)smem + (cur << 15);
        bool domask = (kb + 64 > limB);

#pragma unroll
        for (int kt = 0; kt < 2; kt++) {
            // ---- S^T = K Q^T ----
            f32x16 sc0 = {}, sc1 = {};
#pragma unroll
            for (int h = 0; h < 2; h++) {
                f16x8 ka[4];
#pragma unroll
                for (int i = 0; i < 4; i++)
                    ka[i] = *(const f16x8*)(smc + koff + (h * 4 + i) * 2048 + kt * 512);
#pragma unroll
                for (int i = 0; i < 4; i++) {
                    sc0 = __builtin_amdgcn_mfma_f32_32x32x16_f16(ka[i], bqf[0][h*4+i], sc0, 0, 0, 0);
                    sc1 = __builtin_amdgcn_mfma_f32_32x32x16_f16(ka[i], bqf[1][h*4+i], sc1, 0, 0, 0);
                }
            }

            // ---- mask + exp2 + pack ----
            int w[2][8];
            int keyb = kb + kt * 32 + 4 * lh;
#pragma unroll
            for (int nt = 0; nt < 2; nt++) {
#pragma unroll
                for (int p = 0; p < 8; p++) {
                    const int r0 = 2 * p;
                    float s0 = (nt == 0) ? sc0[r0]     : sc1[r0];
                    float s1 = (nt == 0) ? sc0[r0 + 1] : sc1[r0 + 1];
                    if (domask) {
                        int k0 = keyb + (r0 & 3) + 8 * (r0 >> 2);
                        if (k0     >= lim[nt]) s0 = -1e30f;
                        if (k0 + 1 >= lim[nt]) s1 = -1e30f;
                    }
                    float p0 = fexp2(s0), p1 = fexp2(s1);
                    lpa[nt] += p0;
                    lpb[nt] += p1;
                    PkCast pk; pk.v = __builtin_amdgcn_cvt_pkrtz(p0, p1);
                    w[nt][p] = pk.i;
                }
            }

            // ---- C-layout -> P^T B-frags (cross-half dword exchange) ----
            f16x8 pb[2][2];
#pragma unroll
            for (int nt = 0; nt < 2; nt++)
#pragma unroll
                for (int ks = 0; ks < 2; ks++) {
                    FragCast fc;
#if __has_builtin(__builtin_amdgcn_permlane32_swap)
                    v2i r02 = __builtin_amdgcn_permlane32_swap(w[nt][4*ks+0], w[nt][4*ks+2], false, false);
                    v2i r13 = __builtin_amdgcn_permlane32_swap(w[nt][4*ks+1], w[nt][4*ks+3], false, false);
                    fc.w[0] = r02.x; fc.w[1] = r13.x; fc.w[2] = r02.y; fc.w[3] = r13.y;
#else
                    int w0 = w[nt][4*ks], w1 = w[nt][4*ks+1], w2 = w[nt][4*ks+2], w3 = w[nt][4*ks+3];
                    fc.w[0] = lh ? __shfl_xor(w2, 32) : w0;
                    fc.w[1] = lh ? __shfl_xor(w3, 32) : w1;
                    fc.w[2] = lh ? w2 : __shfl_xor(w0, 32);
                    fc.w[3] = lh ? w3 : __shfl_xor(w1, 32);
#endif
                    pb[nt][ks] = fc.v;
                }

            // ---- O^T += V^T P^T (V frags shared across both n-tiles) ----
#pragma unroll
            for (int mt = 0; mt < 4; mt++)
#pragma unroll
                for (int ks = 0; ks < 2; ks++) {
                    f16x8 va = *(const f16x8*)(smc + 16384 + voff + kt * 8192 + ks * 4096 + mt * 512);
                    oacc[mt][0] = __builtin_amdgcn_mfma_f32_32x32x16_f16(va, pb[0][ks], oacc[mt][0], 0, 0, 0);
                    oacc[mt][1] = __builtin_amdgcn_mfma_f32_32x32x16_f16(va, pb[1][ks], oacc[mt][1], 0, 0, 0);
                }
        }

        // both waves done reading buf[cur] before next iter's stage overwrites it
        __builtin_amdgcn_s_barrier();
        cur ^= 1;
    }

    // ---- l across lane-halves ----
    float lt[2], linv[2];
#pragma unroll
    for (int nt = 0; nt < 2; nt++) {
        float l = lpa[nt] + lpb[nt];
        l += __shfl_xor(l, 32);
        lt[nt] = l;
        linv[nt] = (l > 0.f) ? 1.f / l : 0.f;
    }

    // ---- epilogue through per-wave LDS (swizzled) -> coalesced global ----
    __syncthreads();
    char* ob = (char*)smem + wv * 16384;
#pragma unroll
    for (int mt = 0; mt < 4; mt++)
#pragma unroll
        for (int nt = 0; nt < 2; nt++) {
            int qloc = l31 + 32 * nt;
#pragma unroll
            for (int g4 = 0; g4 < 4; g4++) {
                f16x4 hv;
#pragma unroll
                for (int r = 0; r < 4; r++) hv[r] = (f16)(oacc[mt][nt][g4 * 4 + r] * linv[nt]);
                int c16 = g4 + 4 * mt;
                *(f16x4*)(ob + qloc * 256 + ((c16 ^ (qloc & 7)) << 4) + lh * 8) = hv;
            }
        }
    __syncthreads();

    // slot-compact partial layout: [head][slot=bx][128 q][128 d]
    size_t obase = ((size_t)(head * NSLOT + bx) * 128 + wv * 64) * HD;
#pragma unroll
    for (int a = 0; a < 4; a++)
#pragma unroll
        for (int b = 0; b < 4; b++) {
            int qloc = a * 16 + (lane >> 2);
            int c16  = (lane & 3) + 4 * b;
            f16x8 vv = *(const f16x8*)(ob + qloc * 256 + ((c16 ^ (qloc & 7)) << 4));
            *(f16x8*)(Opart + obase + (size_t)qloc * HD + c16 * 8) = vv;
        }

    if (lane < 32) {
        size_t lbase = (size_t)(head * NSLOT + bx) * 128 + wv * 64;
        lpart[lbase + l31]      = lt[0];
        lpart[lbase + l31 + 32] = lt[1];
    }
}

// ============================================================
// Combine chunk partials -> AO f16 [S][DIM]
// ============================================================
__global__ __launch_bounds__(256) void combine(const f16* __restrict__ Opart,
                                               const float* __restrict__ lpart,
                                               f16* __restrict__ AO) {
    int gid = blockIdx.x * 256 + threadIdx.x;
    if (gid >= S_LEN * NH * 16) return;
    int dc = gid & 15;
    int head = (gid >> 4) % NH;
    int q = gid / (NH * 16);
    int tt = q >> 7, qloc = q & 127;
    int base, nchunk;
    if (tt < 12)      { base = 2 * tt;             nchunk = 2; }
    else if (tt < 24) { base = 24 + 4 * (tt - 12); nchunk = 4; }
    else              { base = 72 + 6 * (tt - 24); nchunk = 6; }

    float sum[8] = {};
    float ls = 0.f;
    for (int c = 0; c < nchunk; c++) {
        size_t sbase = (size_t)(head * NSLOT + base + c) * 128 + qloc;
        float l = lpart[sbase];
        if (l > 0.f) {
            f16x8 o = *(const f16x8*)(Opart + sbase * HD + dc * 8);
#pragma unroll
            for (int j = 0; j < 8; j++) sum[j] += (float)o[j] * l;
            ls += l;
        }
    }
    float invl = 1.f / ls;
    f16x8 r;
#pragma unroll
    for (int j = 0; j < 8; j++) r[j] = (f16)(sum[j] * invl);
    *(f16x8*)(AO + (size_t)q * DIMSZ + head * HD + dc * 8) = r;
}

// ============================================================
// Output projection GEMM (m97 structure), f32 out
// ============================================================
__global__ __launch_bounds__(256) void gemm_lds(const f16* __restrict__ A,
                                                const f16* __restrict__ B,
                                                const float* __restrict__ bias,
                                                float* __restrict__ C) {
    __shared__ __align__(16) f16 Al[128 * 64];
    __shared__ __align__(16) f16 Bl[128 * 64];
    int tid = threadIdx.x;
    int lane = tid & 63, wv = tid >> 6;
    int l16 = lane & 15, quad = lane >> 4;
    int wr = (wv >> 1) * 64, wc = (wv & 1) * 64;
    int m0 = blockIdx.x * 128, n0 = blockIdx.y * 128;

    f32x4 acc[4][4] = {};

    for (int kb = 0; kb < DIMSZ; kb += 64) {
        __syncthreads();
#pragma unroll
        for (int j = 0; j < 4; j++) {
            int s = j * 256 + wv * 64 + lane;
            int r = s >> 3, cc = s & 7;
            const f16* src = A + (size_t)min(m0 + r, S_LEN - 1) * DIMSZ + kb + ((cc ^ (r & 7)) << 3);
            async16(src, (char*)Al + (j * 4096 + wv * 1024));
        }
#pragma unroll
        for (int j = 0; j < 4; j++) {
            int s = j * 256 + wv * 64 + lane;
            int r = s >> 3, cc = s & 7;
            const f16* src = B + (size_t)(n0 + r) * DIMSZ + kb + ((cc ^ (r & 7)) << 3);
            async16(src, (char*)Bl + (j * 4096 + wv * 1024));
        }
        __builtin_amdgcn_s_waitcnt(0x0f70);
        __syncthreads();

#pragma unroll
        for (int kc = 0; kc < 2; kc++) {
            f16x8 af[4], bf[4];
#pragma unroll
            for (int i = 0; i < 4; i++) {
                int ar = wr + i * 16 + l16;
                af[i] = *(const f16x8*)((const char*)Al + ar * 128 + (((kc * 4 + quad) ^ (ar & 7)) << 4));
                int br = wc + i * 16 + l16;
                bf[i] = *(const f16x8*)((const char*)Bl + br * 128 + (((kc * 4 + quad) ^ (br & 7)) << 4));
            }
#pragma unroll
            for (int mi = 0; mi < 4; mi++)
#pragma unroll
                for (int ni = 0; ni < 4; ni++)
                    acc[mi][ni] = __builtin_amdgcn_mfma_f32_16x16x32_f16(af[mi], bf[ni], acc[mi][ni], 0, 0, 0);
        }
    }

#pragma unroll
    for (int mi = 0; mi < 4; mi++)
#pragma unroll
        for (int ni = 0; ni < 4; ni++) {
            int col = n0 + wc + ni * 16 + l16;
            float bv = bias[col];
#pragma unroll
            for (int r = 0; r < 4; r++) {
                int row = m0 + wr + mi * 16 + quad * 4 + r;
                if (row < S_LEN) C[(size_t)row * DIMSZ + col] = acc[mi][ni][r] + bv;
            }
        }
}

// ============================================================
// host launch
// ============================================================
extern "C" void kernel_launch(void* const* d_in, const int* in_sizes, int n_in,
                              void* d_out, int out_size, void* d_ws, size_t ws_size,
                              hipStream_t stream) {
    const float* x     = (const float*)d_in[0];
    const float* freqs = (const float*)d_in[3];
    const float* Wq = (const float*)d_in[4];
    const float* bq = (const float*)d_in[5];
    const float* Wk = (const float*)d_in[6];
    const float* bk = (const float*)d_in[7];
    const float* Wv = (const float*)d_in[8];
    const float* bv = (const float*)d_in[9];
    const float* Wo = (const float*)d_in[10];
    const float* bo = (const float*)d_in[11];
    const float* gq = (const float*)d_in[12];
    const float* gk = (const float*)d_in[13];
    float* out = (float*)d_out;

    char* ws = (char*)d_ws;
    const size_t SZ_XH  = (size_t)S_LEN * DIMSZ * 2;     // 14,376,960
    const size_t SZ_W   = (size_t)DIMSZ * DIMSZ * 2;     //  4,718,592
    const size_t SZ_PAN = (size_t)NH * PANH * 2;         // 14,548,992
    const size_t SZ_OP  = (size_t)NH * NSLOT * 128 * HD * 2;  // 58,982,400

    size_t off = 0;
    f16* xh   = (f16*)(ws + off); off += SZ_XH;
    f16* wqh  = (f16*)(ws + off); off += 4 * SZ_W;       // wq,wk,wv,wo contiguous
    f16* wkh  = wqh + (size_t)DIMSZ * DIMSZ;
    f16* wvh  = wkh + (size_t)DIMSZ * DIMSZ;
    f16* woh  = wvh + (size_t)DIMSZ * DIMSZ;
    f16* Qpan = (f16*)(ws + off); off += SZ_PAN;
    f16* Kpan = (f16*)(ws + off); off += SZ_PAN;
    f16* Vpan = (f16*)(ws + off); off += SZ_PAN;
    // AO aliases Qpan: Qpan is dead after attn_part; combine writes AO
    // strictly after (stream-ordered). Keeps total ws at ~137 MB.
    f16* AO   = Qpan;
    // union: {preq, prek} (f16) before attention | {Opart, lpart} after
    f16*   preq  = (f16*)(ws + off);
    f16*   prek  = preq + (size_t)S_LEN * DIMSZ;
    f16*   Opart = (f16*)(ws + off);
    float* lpart = (float*)(ws + off + SZ_OP);

    cast_all<<<16236, 256, 0, stream>>>(x, Wq, Wk, Wv, Wo, xh, wqh);

    gemm_qkv<<<dim3(37, 12, 3), 256, 0, stream>>>(xh, wqh, wkh, wvh, bq, bk, bv,
                                                  preq, prek, Vpan);

    norm_rope<<<dim3(S_LEN, 2), 256, 0, stream>>>(preq, prek, gq, gk, freqs, Qpan, Kpan);

    attn_part<<<dim3(NSLOT, 12), 128, 0, stream>>>(Qpan, Kpan, Vpan, Opart, lpart);
    combine<<<(S_LEN * NH * 16 + 255) / 256, 256, 0, stream>>>(Opart, lpart, AO);

    gemm_lds<<<dim3(37, 12), 256, 0, stream>>>(AO, woh, bo, out);
}